// Round 10
// baseline (471.960 us; speedup 1.0000x reference)
//
#include <hip/hip_runtime.h>
#include <hip/hip_fp16.h>
#include <cstddef>

#define NA 200000
#define NE 3200000
#define NB 512
#define NBKT 256          // dst-range buckets
#define BKTN 782          // nodes per bucket
#define BKTCAP 16384      // stage capacity per bucket (exp 12500, sigma ~111)
#define NEPB 3200         // edges per pass-1 block (1000*3200 = NE)
#define NGB 3125          // gather blocks: 3125*64 = 200000 = NA exactly

// ---------------- fp16 helpers ----------------
typedef _Float16 hv2 __attribute__((ext_vector_type(2)));
typedef _Float16 half8 __attribute__((ext_vector_type(8)));
typedef float floatx4 __attribute__((ext_vector_type(4)));
union UH2 { unsigned u; __half2 h; hv2 v; };
__device__ __forceinline__ float4 h4f(unsigned a, unsigned b) {
    UH2 x, y; x.u = a; y.u = b;
    float2 fa = __half22float2(x.h), fb = __half22float2(y.h);
    return make_float4(fa.x, fa.y, fb.x, fb.y);
}
__device__ __forceinline__ unsigned f2h(float a, float b) {
    UH2 r; r.h = __float22half2_rn(make_float2(a, b));
    return r.u;
}

// -------- init: accumulator pre-init + weight repack to fp16 ---------------
__global__ void k_init(unsigned* g, int* gcursor,
                       float* gvec, const float* __restrict__ bg2,
                       float* xf2, const float* __restrict__ bf2,
                       float* xf1, const float* __restrict__ bf1,
                       const float* __restrict__ K2, const float* __restrict__ K3,
                       __half* __restrict__ Wt2, __half* __restrict__ Wt3) {
    int i = blockIdx.x * blockDim.x + threadIdx.x;
    if (i < NB * 16) g[i] = 0u;
    if (i < NBKT) gcursor[i] = i * BKTCAP;
    if (i < NB * 128) gvec[i] = bg2[i & 127];
    if (i < NB * 512) xf2[i] = bf2[i & 511];
    if (i < NB * 1024) xf1[i] = bf1[i & 1023];
    if (i < 64 * 32 * 8) {
        int o = i >> 8, rem = i & 255, c = rem >> 3, kk = rem & 7;
        Wt2[(o << 8) + (kk << 5) + c] = __float2half(K2[i]);
    }
    if (i < 128 * 64 * 8) {
        int o = i >> 9, rem = i & 511, c = rem >> 3, kk = rem & 7;
        Wt3[(o << 9) + (kk << 6) + c] = __float2half(K3[i]);
    }
}

// ------- conv1 device body (fp32 LDS/compute, fp16 output) -----------------
// PT=1: live set ~50 regs (acc[12]+xa[20]+wa[8]+addr) -> fits the 64-VGPR
// budget of launch_bounds(256,8) WITHOUT spills (R7 lesson: never force
// below the live set; here we shrink the live set first, then pin).
// Per-output FP sequence identical to PT=4 (bit-identical results).
template<int CIN, int COUT, int OBLK, int LIN, int PITCH, int POUT, int NTT>
__device__ __forceinline__ void dev_conv1(int b, int oy,
        const float* __restrict__ in, const float* __restrict__ Kw,
        const float* __restrict__ bias, __half* __restrict__ out,
        float* s_in) {
    constexpr int SPO = 256 / OBLK;
    for (int idx = threadIdx.x; idx < CIN * PITCH; idx += 256) s_in[idx] = 0.f;
    __syncthreads();
    for (int idx = threadIdx.x; idx < LIN * CIN; idx += 256) {
        int p = idx / CIN, c = idx - p * CIN;
        s_in[c * PITCH + p] = in[(size_t)b * (LIN * CIN) + idx];
    }
    __syncthreads();
    int ol = threadIdx.x / SPO;
    int s  = threadIdx.x - ol * SPO;
    int o  = oy * OBLK + ol;
    float bo = bias[o];
    const float* wrow = Kw + (size_t)o * CIN * 8;
    for (int pass = 0; pass < NTT; pass++) {
        float acc[12];
#pragma unroll
        for (int j = 0; j < 12; j++) acc[j] = 0.f;
        int tg = s + SPO * pass;
        bool vld = (4 * tg < POUT);
        for (int i = 0; i < CIN; i++) {
            float wa[8];
            const float4* wp = (const float4*)(wrow + (size_t)i * 8);
            *(float4*)&wa[0] = wp[0];
            *(float4*)&wa[4] = wp[1];
            if (vld) {
                const float4* xr = (const float4*)&s_in[i * PITCH + 12 * tg];
                float xa[20];
#pragma unroll
                for (int q = 0; q < 5; q++) *(float4*)&xa[4 * q] = xr[q];
#pragma unroll
                for (int j = 0; j < 12; j++) {
                    float sm = acc[j];
#pragma unroll
                    for (int k = 0; k < 8; k++) sm = fmaf(xa[j + k], wa[k], sm);
                    acc[j] = sm;
                }
            }
        }
        if (vld) {
#pragma unroll
            for (int p = 0; p < 4; p++) {
                int P = 4 * tg + p;
                if (P < POUT) {
                    float m = fmaxf(fmaxf(acc[3 * p], acc[3 * p + 1]), acc[3 * p + 2]);
                    out[((size_t)b * COUT + o) * POUT + P] = __float2half(fmaxf(m + bo, 0.f));
                }
            }
        }
    }
}

// ======================= MFMA conv2 ========================================
__device__ __forceinline__ void dev_conv2_mfma(int b,
        const __half* __restrict__ pool1, const __half* __restrict__ Wt2,
        const float* __restrict__ cb2, __half* __restrict__ pool2t,
        char* smem) {
    __half* sT   = (__half*)smem;   // [344][40] halves = 27520 B
    __half* outS = (__half*)smem;   // [336][68] halves = 45696 B (overlays sT)
    const __half* inp = pool1 + (size_t)b * (32 * 331);
    for (int idx = threadIdx.x; idx < 32 * 331; idx += 256) {
        int c = idx / 331;
        int p = idx - c * 331;
        sT[p * 40 + c] = inp[idx];              // LDS transpose (2B scattered)
    }
    __syncthreads();
    int lane = threadIdx.x & 63, wv = threadIdx.x >> 6;
    int l15 = lane & 15, lg = lane >> 4;
    int mtBeg = wv * 5;
    int nmt = (wv == 3) ? 6 : 5;
    const floatx4 FZ = {0.f, 0.f, 0.f, 0.f};
    floatx4 acc[6][4];
#pragma unroll
    for (int mi = 0; mi < 6; mi++)
#pragma unroll
        for (int nt = 0; nt < 4; nt++) acc[mi][nt] = FZ;
    const half8* WB = (const half8*)Wt2;
    for (int s = 0; s < 8; s++) {
        half8 bfr[4];
#pragma unroll
        for (int nt = 0; nt < 4; nt++)
            bfr[nt] = WB[(nt * 16 + l15) * 32 + s * 4 + lg];
        half8 afr[6];
#pragma unroll
        for (int mi = 0; mi < 6; mi++) {
            if (mi < nmt) {
                int row = (mtBeg + mi) * 16 + l15 + s;
                afr[mi] = *(const half8*)(sT + row * 40 + lg * 8);
            }
        }
#pragma unroll
        for (int mi = 0; mi < 6; mi++) {
            if (mi < nmt) {
#pragma unroll
                for (int nt = 0; nt < 4; nt++)
                    acc[mi][nt] = __builtin_amdgcn_mfma_f32_16x16x32_f16(
                        afr[mi], bfr[nt], acc[mi][nt], 0, 0, 0);
            }
        }
    }
    __syncthreads();                              // sT reads done; overlay outS
    float bo[4];
#pragma unroll
    for (int nt = 0; nt < 4; nt++) bo[nt] = cb2[nt * 16 + l15];
#pragma unroll
    for (int mi = 0; mi < 6; mi++) {
        if (mi < nmt) {
#pragma unroll
            for (int nt = 0; nt < 4; nt++) {
                int o = nt * 16 + l15;
#pragma unroll
                for (int r = 0; r < 4; r++) {
                    int p = (mtBeg + mi) * 16 + lg * 4 + r;
                    float v = fmaxf(acc[mi][nt][r] + bo[nt], 0.f);
                    outS[p * 68 + o] = __float2half(v);
                }
            }
        }
    }
    __syncthreads();
    __half* op = pool2t + (size_t)b * (108 * 64);
    for (int idx = threadIdx.x; idx < 108 * 64; idx += 256) {
        int P = idx >> 6, o = idx & 63;
        float v0 = __half2float(outS[(3 * P) * 68 + o]);
        float v1 = __half2float(outS[(3 * P + 1) * 68 + o]);
        float v2 = __half2float(outS[(3 * P + 2) * 68 + o]);
        op[idx] = __float2half(fmaxf(fmaxf(v0, v1), v2));   // [b][P][o]
    }
}

// ======================= MFMA conv3 (N-split halves) =======================
// acc[2][4] (32 VGPR): fused kernel's natural live set fits the <=64 bucket
// so launch_bounds(256,8) is SAFE here (verified: k_C Occ 50-65%, no spill).
__device__ __forceinline__ void dev_conv3_mfma(int b, int nh,
        const __half* __restrict__ pool2t, const __half* __restrict__ Wt3,
        const float* __restrict__ cb3, float* __restrict__ pool3,
        char* smem) {
    __half* sT  = (__half*)smem;   // [120][72] halves = 17280 B
    float* outS = (float*)smem;    // [48][68] fp32 = 13056 B (overlays sT)
    const uint4* inp = (const uint4*)(pool2t + (size_t)b * (108 * 64));
    for (int t = threadIdx.x; t < 108 * 8; t += 256) {
        int r = t >> 3, s8 = t & 7;
        *(uint4*)(sT + r * 72 + s8 * 8) = inp[t];
    }
    __syncthreads();
    int lane = threadIdx.x & 63, wv = threadIdx.x >> 6;
    int l15 = lane & 15, lg = lane >> 4;
    int mtBeg = wv * 2;
    int nmt = (wv == 3) ? 1 : 2;
    const floatx4 FZ = {0.f, 0.f, 0.f, 0.f};
    floatx4 acc[2][4];
#pragma unroll
    for (int mi = 0; mi < 2; mi++)
#pragma unroll
        for (int nt = 0; nt < 4; nt++) acc[mi][nt] = FZ;
    const half8* WB = (const half8*)Wt3;
    for (int s = 0; s < 16; s++) {
        half8 afr[2];
#pragma unroll
        for (int mi = 0; mi < 2; mi++) {
            if (mi < nmt) {
                int row = (mtBeg + mi) * 16 + l15 + (s >> 1);
                afr[mi] = *(const half8*)(sT + row * 72 + (s & 1) * 32 + lg * 8);
            }
        }
#pragma unroll
        for (int nt = 0; nt < 4; nt++) {
            half8 bfr = WB[((nh * 4 + nt) * 16 + l15) * 64 + s * 4 + lg];
            acc[0][nt] = __builtin_amdgcn_mfma_f32_16x16x32_f16(
                afr[0], bfr, acc[0][nt], 0, 0, 0);
            if (nmt > 1)
                acc[1][nt] = __builtin_amdgcn_mfma_f32_16x16x32_f16(
                    afr[1], bfr, acc[1][nt], 0, 0, 0);
        }
    }
    __syncthreads();                              // MFMA done; sT dead
    float bo[4];
#pragma unroll
    for (int nt = 0; nt < 4; nt++) bo[nt] = cb3[(nh * 4 + nt) * 16 + l15];
    float* op = pool3 + (size_t)b * (33 * 128);
    for (int pp = 0; pp < 3; pp++) {
        int t0 = 3 * pp;
#pragma unroll
        for (int mi = 0; mi < 2; mi++) {
            int tile = mtBeg + mi;
            if (mi < nmt && tile >= t0 && tile < t0 + 3) {
#pragma unroll
                for (int nt = 0; nt < 4; nt++) {
                    int ol = nt * 16 + l15;
#pragma unroll
                    for (int r = 0; r < 4; r++) {
                        int p = tile * 16 + lg * 4 + r;
                        if (p < 100)
                            outS[(p - 48 * pp) * 68 + ol] =
                                fmaxf(acc[mi][nt][r] + bo[nt], 0.f);
                    }
                }
            }
        }
        __syncthreads();
        int nP = (pp == 2) ? 1 : 16;
        for (int idx = threadIdx.x; idx < nP * 64; idx += 256) {
            int Pl = idx >> 6, ol = idx & 63;
            int P = 16 * pp + Pl;
            int p = 3 * P - 48 * pp;
            float v0 = outS[p * 68 + ol];
            float v1 = outS[(p + 1) * 68 + ol];
            float v2 = outS[(p + 2) * 68 + ol];
            op[P * 128 + (nh << 6) + ol] = fmaxf(fmaxf(v0, v1), v2);
        }
        __syncthreads();
    }
}

// -------- K_A: pass1 edge binning w/ LDS sort (1000) || conv1 oy=0 (512) ---
// launch_bounds(256,8): conv1 PT=1 live set ~50 fits the 64-VGPR budget.
__global__ __launch_bounds__(256, 8) void k_A(
        const int* __restrict__ src, const int* __restrict__ dst,
        int* __restrict__ gcursor, unsigned* __restrict__ stage,
        const float* __restrict__ tgt, const float* __restrict__ K1,
        const float* __restrict__ cb1, __half* __restrict__ pool1) {
    __shared__ __align__(16) char smem[20160];   // conv1 s_in OR sort arrays
    int bx = blockIdx.x;
    if (bx >= 1000) {
        dev_conv1<5, 32, 16, 1000, 1008, 331, 6>(bx - 1000, 0, tgt, K1, cb1,
                                                 pool1, (float*)smem);
        return;
    }
    int* hcnt  = (int*)smem;                 // [256] count -> scan -> cursor
    int* hbase = hcnt + 256;                 // [256] global bucket base
    int* lbase = hbase + 256;                // [256] local bucket base
    unsigned* sbuf = (unsigned*)(lbase + 256);      // [3200] sorted entries
    unsigned char* sbkt = (unsigned char*)(sbuf + NEPB); // [3200] bucket ids
    int t = threadIdx.x;
    int e0 = bx * NEPB;
    hcnt[t] = 0;
    __syncthreads();
    const int4* d4 = (const int4*)(dst + e0);
    for (int i = t; i < NEPB / 4; i += 256) {
        int4 d = d4[i];
        atomicAdd(&hcnt[d.x / BKTN], 1);
        atomicAdd(&hcnt[d.y / BKTN], 1);
        atomicAdd(&hcnt[d.z / BKTN], 1);
        atomicAdd(&hcnt[d.w / BKTN], 1);
    }
    __syncthreads();
    int myc = hcnt[t];
    hbase[t] = atomicAdd(&gcursor[t], myc);
    __syncthreads();
    // in-place inclusive scan of hcnt (Hillis-Steele)
#pragma unroll
    for (int off = 1; off < 256; off <<= 1) {
        int u = (t >= off) ? hcnt[t - off] : 0;
        __syncthreads();
        hcnt[t] += u;
        __syncthreads();
    }
    lbase[t] = hcnt[t] - myc;   // exclusive base
    hcnt[t] = 0;                // reuse as per-bucket cursor
    __syncthreads();
    const int4* s4 = (const int4*)(src + e0);
    for (int i = t; i < NEPB / 4; i += 256) {
        int4 d = d4[i];
        int4 s = s4[i];
        int ds[4] = {d.x, d.y, d.z, d.w};
        int ss[4] = {s.x, s.y, s.z, s.w};
#pragma unroll
        for (int j = 0; j < 4; j++) {
            int bkt = ds[j] / BKTN;
            int dloc = ds[j] - bkt * BKTN;
            int k = atomicAdd(&hcnt[bkt], 1);
            int pos = lbase[bkt] + k;
            sbuf[pos] = ((unsigned)dloc << 18) | (unsigned)ss[j];
            sbkt[pos] = (unsigned char)bkt;
        }
    }
    __syncthreads();
    // coalesced copy-out: consecutive i -> consecutive stage addresses
    for (int i = t; i < NEPB; i += 256) {
        unsigned v = sbuf[i];
        int bkt = sbkt[i];
        stage[hbase[bkt] + (i - lbase[bkt])] = v;
    }
}

// -------- K_Bp: pass2 (256) || conv1 oy=1 (512) ----------------------------
__global__ __launch_bounds__(256, 8) void k_Bp(
        const unsigned* __restrict__ stage, const int* __restrict__ gcursor,
        int* __restrict__ rowptr, int* __restrict__ cnt, int* __restrict__ csr,
        const float* __restrict__ x, float4* __restrict__ dt1,
        const float* __restrict__ tgt, const float* __restrict__ K1,
        const float* __restrict__ cb1, __half* __restrict__ pool1) {
    __shared__ __align__(16) char smem[20160];   // conv1 s_in OR pass2 arrays
    __shared__ int sbase;
    int bx = blockIdx.x;
    if (bx >= NBKT) {
        dev_conv1<5, 32, 16, 1000, 1008, 331, 6>(bx - NBKT, 1, tgt, K1, cb1,
                                                 pool1, (float*)smem);
        return;
    }
    int* lcnt    = (int*)smem;       // [782]
    int* lpos    = lcnt + BKTN;      // [782]
    int* partial = lpos + BKTN;      // [256]
    int t = threadIdx.x;
    int bkt = bx;
    int tot = gcursor[t] - t * BKTCAP;
    partial[t] = tot;
    __syncthreads();
#pragma unroll
    for (int off = 1; off < 256; off <<= 1) {
        int u = (t >= off) ? partial[t - off] : 0;
        __syncthreads();
        partial[t] += u;
        __syncthreads();
    }
    if (t == 0) sbase = (bkt == 0) ? 0 : partial[bkt - 1];
    __syncthreads();
    int base = sbase;
    int n0 = bkt * BKTN;
    int ncnt = (NA - n0 < BKTN) ? (NA - n0) : BKTN;
    int eBeg = bkt * BKTCAP;
    int eCnt = gcursor[bkt] - eBeg;
    for (int i = t; i < BKTN; i += 256) lcnt[i] = 0;
    __syncthreads();
    for (int i = t; i < eCnt; i += 256)
        atomicAdd(&lcnt[stage[eBeg + i] >> 18], 1);
    __syncthreads();
    int mysum = 0;
#pragma unroll
    for (int j = 0; j < 4; j++) {
        int node = 4 * t + j;
        if (node < ncnt) mysum += lcnt[node];
    }
    partial[t] = mysum;
    __syncthreads();
#pragma unroll
    for (int off = 1; off < 256; off <<= 1) {
        int u = (t >= off) ? partial[t - off] : 0;
        __syncthreads();
        partial[t] += u;
        __syncthreads();
    }
    int running = partial[t] - mysum;
#pragma unroll
    for (int j = 0; j < 4; j++) {
        int node = 4 * t + j;
        if (node < ncnt) {
            lpos[node] = running;
            rowptr[n0 + node] = base + running;
            cnt[n0 + node] = lcnt[node];
            running += lcnt[node];
        }
    }
    __syncthreads();
    for (int i = t; i < eCnt; i += 256) {
        unsigned v = stage[eBeg + i];
        int dloc = v >> 18;
        int s = v & 0x3FFFF;
        int k = atomicAdd(&lpos[dloc], 1);
        csr[base + k] = s;
    }
    for (int i = t; i < ncnt; i += 256) {
        int n = n0 + i;
        float4 p = ((const float4*)x)[n];
        float dv = rsqrtf((float)lcnt[i] + 1.0f);
        dt1[n] = make_float4(dv * p.x, dv * p.y, dv * p.z, dv * p.w);
    }
}

// -------- K_B: conv2 MFMA (512) || coop-gather1+W1 -> dt2 (3125) -----------
// 4 lanes/node: lane sub loads neighbors e=sub,sub+4,..., butterfly shfl_xor
// combines; lane sub computes output f=sub; 4B coalesced write.
__global__ __launch_bounds__(256) void k_B(
        const __half* __restrict__ pool1, const __half* __restrict__ Wt2,
        const float* __restrict__ cb2, __half* __restrict__ pool2t,
        const float4* __restrict__ dt1, const int* __restrict__ rowptr,
        const int* __restrict__ cnt, const int* __restrict__ csr,
        const float* __restrict__ W1, const float* __restrict__ b1,
        float* __restrict__ dt2f) {
    __shared__ __align__(16) char smem[45696];
    int bx = blockIdx.x;
    if (bx < 512) {
        dev_conv2_mfma(bx, pool1, Wt2, cb2, pool2t, smem);
        return;
    }
    __shared__ float sW[16];
    if (threadIdx.x < 16) sW[threadIdx.x] = W1[threadIdx.x];
    __syncthreads();
    int n   = (bx - 512) * 64 + (threadIdx.x >> 2);   // always < NA
    int sub = threadIdx.x & 3;
    int cn = cnt[n];
    float dv = rsqrtf((float)cn + 1.0f);
    const int* row = csr + rowptr[n];
    float4 selfv = dt1[n];                            // broadcast load
    float4 acc = make_float4(0.f, 0.f, 0.f, 0.f);
    if (sub == 0) acc = selfv;
    int e = sub;
    for (; e + 4 < cn; e += 8) {                      // 2 independent loads
        float4 v0 = dt1[row[e]];
        float4 v1 = dt1[row[e + 4]];
        acc.x += v0.x + v1.x; acc.y += v0.y + v1.y;
        acc.z += v0.z + v1.z; acc.w += v0.w + v1.w;
    }
    if (e < cn) {
        float4 v = dt1[row[e]];
        acc.x += v.x; acc.y += v.y; acc.z += v.z; acc.w += v.w;
    }
    // butterfly over the 4-lane group
    acc.x += __shfl_xor(acc.x, 1); acc.y += __shfl_xor(acc.y, 1);
    acc.z += __shfl_xor(acc.z, 1); acc.w += __shfl_xor(acc.w, 1);
    acc.x += __shfl_xor(acc.x, 2); acc.y += __shfl_xor(acc.y, 2);
    acc.z += __shfl_xor(acc.z, 2); acc.w += __shfl_xor(acc.w, 2);
    float a[4] = {acc.x, acc.y, acc.z, acc.w};
    float s = 0.f;
#pragma unroll
    for (int k = 0; k < 4; k++) s = fmaf(a[k], sW[k * 4 + sub], s);
    float o = dv * fmaxf(fmaf(dv, s, b1[sub]), 0.f);  // dt2 = dv*relu(...)
    dt2f[(size_t)n * 4 + sub] = o;
}

// -------- K_C: conv3 N-split (1024) || coop-gather2+W2 -> dt3 (3125) -------
// launch_bounds(256,8): fused live set ~32 regs, no spill risk (verified).
__global__ __launch_bounds__(256, 8) void k_C(
        const __half* __restrict__ pool2t, const __half* __restrict__ Wt3,
        const float* __restrict__ cb3, float* __restrict__ pool3,
        const float4* __restrict__ dt2, const int* __restrict__ rowptr,
        const int* __restrict__ cnt, const int* __restrict__ csr,
        const float* __restrict__ W2, const float* __restrict__ b2,
        unsigned* __restrict__ dt3u) {
    __shared__ __align__(16) char smem[17280];
    int bx = blockIdx.x;
    if (bx < 1024) {
        dev_conv3_mfma(bx & 511, bx >> 9, pool2t, Wt3, cb3, pool3, smem);
        return;
    }
    __shared__ float sW[32];
    if (threadIdx.x < 32) sW[threadIdx.x] = W2[threadIdx.x];
    __syncthreads();
    int n   = (bx - 1024) * 64 + (threadIdx.x >> 2);
    int sub = threadIdx.x & 3;
    int cn = cnt[n];
    float dv = rsqrtf((float)cn + 1.0f);
    const int* row = csr + rowptr[n];
    float4 selfv = dt2[n];
    float4 acc = make_float4(0.f, 0.f, 0.f, 0.f);
    if (sub == 0) acc = selfv;
    int e = sub;
    for (; e + 4 < cn; e += 8) {
        float4 v0 = dt2[row[e]];
        float4 v1 = dt2[row[e + 4]];
        acc.x += v0.x + v1.x; acc.y += v0.y + v1.y;
        acc.z += v0.z + v1.z; acc.w += v0.w + v1.w;
    }
    if (e < cn) {
        float4 v = dt2[row[e]];
        acc.x += v.x; acc.y += v.y; acc.z += v.z; acc.w += v.w;
    }
    acc.x += __shfl_xor(acc.x, 1); acc.y += __shfl_xor(acc.y, 1);
    acc.z += __shfl_xor(acc.z, 1); acc.w += __shfl_xor(acc.w, 1);
    acc.x += __shfl_xor(acc.x, 2); acc.y += __shfl_xor(acc.y, 2);
    acc.z += __shfl_xor(acc.z, 2); acc.w += __shfl_xor(acc.w, 2);
    float a[4] = {acc.x, acc.y, acc.z, acc.w};
    int f0 = 2 * sub;
    float s0 = 0.f, s1 = 0.f;
#pragma unroll
    for (int k = 0; k < 4; k++) {
        s0 = fmaf(a[k], sW[k * 8 + f0], s0);
        s1 = fmaf(a[k], sW[k * 8 + f0 + 1], s1);
    }
    float o0 = dv * fmaxf(fmaf(dv, s0, b2[f0]), 0.f);
    float o1 = dv * fmaxf(fmaf(dv, s1, b2[f0 + 1]), 0.f);
    dt3u[(size_t)n * 4 + sub] = f2h(o0, o1);
}

// -------- K_D: coop-gather3(fp16)+W3+segmax (3125) || mean+Wxt (64) --------
__global__ __launch_bounds__(256) void k_D(
        const uint4* __restrict__ dt3, const int* __restrict__ rowptr,
        const int* __restrict__ cnt, const int* __restrict__ csr,
        const float* __restrict__ W3, const float* __restrict__ b3,
        const int* __restrict__ batch, unsigned* __restrict__ g,
        const float* __restrict__ pool3, const float* __restrict__ Wxt,
        const float* __restrict__ bxt, float* __restrict__ cx) {
    int bx = blockIdx.x;
    if (bx >= NGB) {
        __shared__ float sa[8 * 128];
        int b0 = (bx - NGB) * 8;
        for (int t = threadIdx.x; t < 8 * 128; t += 256) {
            int gg = t >> 7, k = t & 127;
            // pool3 layout [b][P=33][o=128]; lanes read consecutive o
            const float* r = pool3 + (size_t)(b0 + gg) * (33 * 128) + k;
            float s = 0.f;
#pragma unroll
            for (int p = 0; p < 33; p++) s += r[p * 128];
            sa[t] = s * (1.f / 33.f);
        }
        __syncthreads();
        int j = threadIdx.x;
        if (j >= 128) return;
        float bj = bxt[j];
        float acc[8];
#pragma unroll
        for (int gg = 0; gg < 8; gg++) acc[gg] = bj;
#pragma unroll 4
        for (int k = 0; k < 128; k++) {
            float w = Wxt[(size_t)k * 128 + j];
#pragma unroll
            for (int gg = 0; gg < 8; gg++) acc[gg] = fmaf(sa[gg * 128 + k], w, acc[gg]);
        }
#pragma unroll
        for (int gg = 0; gg < 8; gg++)
            cx[(size_t)(b0 + gg) * 128 + j] = fmaxf(acc[gg], 0.f);
        return;
    }
    __shared__ float sW[128];
    __shared__ unsigned sg[32];
    __shared__ int sbmin;
    if (threadIdx.x < 128) sW[threadIdx.x] = W3[threadIdx.x];
    if (threadIdx.x < 32) sg[threadIdx.x] = 0u;
    if (threadIdx.x == 0) sbmin = batch[bx * 64];
    __syncthreads();
    int n   = bx * 64 + (threadIdx.x >> 2);          // always < NA
    int sub = threadIdx.x & 3;
    int cn = cnt[n];
    float dv = rsqrtf((float)cn + 1.0f);
    const int* row = csr + rowptr[n];
    uint4 sv = dt3[n];
    float4 slo = h4f(sv.x, sv.y), shi = h4f(sv.z, sv.w);
    float a0 = 0.f, a1 = 0.f, a2 = 0.f, a3 = 0.f;
    float a4 = 0.f, a5 = 0.f, a6 = 0.f, a7 = 0.f;
    if (sub == 0) {
        a0 = slo.x; a1 = slo.y; a2 = slo.z; a3 = slo.w;
        a4 = shi.x; a5 = shi.y; a6 = shi.z; a7 = shi.w;
    }
    int e = sub;
    for (; e + 4 < cn; e += 8) {
        uint4 p0 = dt3[row[e]], p1 = dt3[row[e + 4]];
        float4 l0 = h4f(p0.x, p0.y), h0 = h4f(p0.z, p0.w);
        float4 l1 = h4f(p1.x, p1.y), h1 = h4f(p1.z, p1.w);
        a0 += l0.x + l1.x; a1 += l0.y + l1.y;
        a2 += l0.z + l1.z; a3 += l0.w + l1.w;
        a4 += h0.x + h1.x; a5 += h0.y + h1.y;
        a6 += h0.z + h1.z; a7 += h0.w + h1.w;
    }
    if (e < cn) {
        uint4 p = dt3[row[e]];
        float4 l = h4f(p.x, p.y), h = h4f(p.z, p.w);
        a0 += l.x; a1 += l.y; a2 += l.z; a3 += l.w;
        a4 += h.x; a5 += h.y; a6 += h.z; a7 += h.w;
    }
    a0 += __shfl_xor(a0, 1); a1 += __shfl_xor(a1, 1);
    a2 += __shfl_xor(a2, 1); a3 += __shfl_xor(a3, 1);
    a4 += __shfl_xor(a4, 1); a5 += __shfl_xor(a5, 1);
    a6 += __shfl_xor(a6, 1); a7 += __shfl_xor(a7, 1);
    a0 += __shfl_xor(a0, 2); a1 += __shfl_xor(a1, 2);
    a2 += __shfl_xor(a2, 2); a3 += __shfl_xor(a3, 2);
    a4 += __shfl_xor(a4, 2); a5 += __shfl_xor(a5, 2);
    a6 += __shfl_xor(a6, 2); a7 += __shfl_xor(a7, 2);
    float af[8] = {a0, a1, a2, a3, a4, a5, a6, a7};
    int rb = batch[n] - sbmin;
    if (rb > 1) rb = 1;
#pragma unroll
    for (int j = 0; j < 4; j++) {
        int f = sub * 4 + j;
        float s = 0.f;
#pragma unroll
        for (int k = 0; k < 8; k++) s = fmaf(af[k], sW[k * 16 + f], s);
        float r = fmaxf(fmaf(dv, s, b3[f]), 0.f);
        atomicMax(&sg[rb * 16 + f], __float_as_uint(r));
    }
    __syncthreads();
    if (threadIdx.x < 32) {
        unsigned v = sg[threadIdx.x];
        int rb2 = threadIdx.x >> 4, f = threadIdx.x & 15;
        int bbn = sbmin + rb2;
        if (v != 0u && bbn < NB) atomicMax(&g[bbn * 16 + f], v);
    }
}

// -------- head: g@Wg1 -> gp1 (relu), 256 blocks ----------------------------
__global__ __launch_bounds__(256) void k_head_g(
        const float* __restrict__ g, const float* __restrict__ Wg1,
        const float* __restrict__ bg1, float* __restrict__ gp1) {
    __shared__ float sa[8 * 16];
    int bx = blockIdx.x;
    int b0 = (bx >> 2) * 8;
    if (threadIdx.x < 128)
        sa[threadIdx.x] = g[b0 * 16 + threadIdx.x];
    __syncthreads();
    int j = (bx & 3) * 256 + threadIdx.x;
    float bj = bg1[j];
    float acc[8];
#pragma unroll
    for (int gg = 0; gg < 8; gg++) acc[gg] = bj;
#pragma unroll
    for (int k = 0; k < 16; k++) {
        float w = Wg1[(size_t)k * 1024 + j];
#pragma unroll
        for (int gg = 0; gg < 8; gg++) acc[gg] = fmaf(sa[gg * 16 + k], w, acc[gg]);
    }
#pragma unroll
    for (int gg = 0; gg < 8; gg++)
        gp1[(size_t)(b0 + gg) * 1024 + j] = fmaxf(acc[gg], 0.f);
}

// -------- gvec += (gp1 K-slice)@Wg2 ; grid (8,64), 16-deep batching --------
__global__ __launch_bounds__(256) void k_gvec_ks(
        const float* __restrict__ gp1, const float* __restrict__ Wg2,
        float* __restrict__ gvec) {
    __shared__ float sa[8 * 128];
    int k0 = blockIdx.x * 128;
    int b0 = blockIdx.y * 8;
    for (int t = threadIdx.x; t < 8 * 128; t += 256) {
        int gg = t >> 7, k = t & 127;
        sa[t] = gp1[(size_t)(b0 + gg) * 1024 + k0 + k];
    }
    __syncthreads();
    int j  = threadIdx.x & 127;
    int kh = (threadIdx.x >> 7) * 64;            // 0 or 64
    const float* Wp = Wg2 + (size_t)(k0 + kh) * 128 + j;
    float acc[8];
#pragma unroll
    for (int gg = 0; gg < 8; gg++) acc[gg] = 0.f;
    for (int k = 0; k < 64; k += 16) {
        float w[16];
#pragma unroll
        for (int u = 0; u < 16; u++) w[u] = Wp[(size_t)(k + u) * 128];
#pragma unroll
        for (int u = 0; u < 16; u++) {
#pragma unroll
            for (int gg = 0; gg < 8; gg++)
                acc[gg] = fmaf(sa[gg * 128 + kh + k + u], w[u], acc[gg]);
        }
    }
#pragma unroll
    for (int gg = 0; gg < 8; gg++)
        atomicAdd(&gvec[(size_t)(b0 + gg) * 128 + j], acc[gg]);
}

// -------- xf1 += ([gvec|cx] K-half)@Wf1 ; grid (8,64): 4j x 2kh ------------
__global__ __launch_bounds__(256) void k_cat2(
        const float* __restrict__ gvec, const float* __restrict__ cx,
        const float* __restrict__ Wf1, float* __restrict__ xf1) {
    __shared__ float sa[8 * 128];
    int jx = blockIdx.x & 3;
    int kh = blockIdx.x >> 2;                    // 0: gvec rows, 1: cx rows
    int b0 = blockIdx.y * 8;
    const float* A = kh ? cx : gvec;
    for (int t = threadIdx.x; t < 8 * 128; t += 256) {
        int gg = t >> 7, k = t & 127;
        sa[t] = A[(size_t)(b0 + gg) * 128 + k];
    }
    __syncthreads();
    int j = jx * 256 + threadIdx.x;
    const float* Wp = Wf1 + (size_t)(kh * 128) * 1024 + j;
    float acc[8];
#pragma unroll
    for (int gg = 0; gg < 8; gg++) acc[gg] = 0.f;
    for (int k = 0; k < 128; k += 16) {
        float w[16];
#pragma unroll
        for (int u = 0; u < 16; u++) w[u] = Wp[(size_t)(k + u) * 1024];
#pragma unroll
        for (int u = 0; u < 16; u++) {
#pragma unroll
            for (int gg = 0; gg < 8; gg++)
                acc[gg] = fmaf(sa[gg * 128 + k + u], w[u], acc[gg]);
        }
    }
#pragma unroll
    for (int gg = 0; gg < 8; gg++)
        atomicAdd(&xf1[(size_t)(b0 + gg) * 1024 + j], acc[gg]);
}

// -------- xf2 += relu(xf1 K-slice)@Wf2 ; grid (8,64): 2j x 4kc -------------
__global__ __launch_bounds__(256) void k_xf2_ks(
        const float* __restrict__ xf1, const float* __restrict__ Wf2,
        float* __restrict__ xf2) {
    __shared__ float sa[8 * 256];
    int jb = blockIdx.x & 1;
    int k0 = (blockIdx.x >> 1) * 256;
    int b0 = blockIdx.y * 8;
    for (int t = threadIdx.x; t < 8 * 256; t += 256) {
        int gg = t >> 8, k = t & 255;
        sa[t] = fmaxf(xf1[(size_t)(b0 + gg) * 1024 + k0 + k], 0.f);  // deferred relu
    }
    __syncthreads();
    int j = jb * 256 + threadIdx.x;
    const float* Wp = Wf2 + (size_t)k0 * 512 + j;
    float acc[8];
#pragma unroll
    for (int gg = 0; gg < 8; gg++) acc[gg] = 0.f;
    for (int k = 0; k < 256; k += 16) {
        float w[16];
#pragma unroll
        for (int u = 0; u < 16; u++) w[u] = Wp[(size_t)(k + u) * 512];
#pragma unroll
        for (int u = 0; u < 16; u++) {
#pragma unroll
            for (int gg = 0; gg < 8; gg++)
                acc[gg] = fmaf(sa[gg * 256 + k + u], w[u], acc[gg]);
        }
    }
#pragma unroll
    for (int gg = 0; gg < 8; gg++)
        atomicAdd(&xf2[(size_t)(b0 + gg) * 512 + j], acc[gg]);
}

// final 512->2 layer; applies the deferred relu on xf2; float4 A-loads
__global__ __launch_bounds__(256) void k_dense_out(
        const float* __restrict__ A, const float* __restrict__ W,
        const float* __restrict__ bias, float* __restrict__ out) {
    int idx = blockIdx.x * 256 + threadIdx.x;
    if (idx >= NB * 2) return;
    int b = idx >> 1, j = idx & 1;
    float s = bias[j];
    const float4* A4 = (const float4*)(A + (size_t)b * 512);
    for (int k4 = 0; k4 < 128; k4 += 8) {
        float4 av[8];
#pragma unroll
        for (int u = 0; u < 8; u++) av[u] = A4[k4 + u];
#pragma unroll
        for (int u = 0; u < 8; u++) {
            int kb = (k4 + u) * 4;
            s = fmaf(fmaxf(av[u].x, 0.f), W[(kb + 0) * 2 + j], s);
            s = fmaf(fmaxf(av[u].y, 0.f), W[(kb + 1) * 2 + j], s);
            s = fmaf(fmaxf(av[u].z, 0.f), W[(kb + 2) * 2 + j], s);
            s = fmaf(fmaxf(av[u].w, 0.f), W[(kb + 3) * 2 + j], s);
        }
    }
    out[idx] = s;
}

extern "C" void kernel_launch(void* const* d_in, const int* in_sizes, int n_in,
                              void* d_out, int out_size, void* d_ws, size_t ws_size,
                              hipStream_t stream) {
    (void)in_sizes; (void)n_in; (void)out_size; (void)ws_size;
    const float* x   = (const float*)d_in[0];
    const int*  ei   = (const int*)d_in[1];
    const int*  batch= (const int*)d_in[2];
    const float* tgt = (const float*)d_in[3];
    const float* W1  = (const float*)d_in[4];  const float* b1  = (const float*)d_in[5];
    const float* W2  = (const float*)d_in[6];  const float* b2  = (const float*)d_in[7];
    const float* W3  = (const float*)d_in[8];  const float* b3  = (const float*)d_in[9];
    const float* Wg1 = (const float*)d_in[10]; const float* bg1 = (const float*)d_in[11];
    const float* Wg2 = (const float*)d_in[12]; const float* bg2 = (const float*)d_in[13];
    const float* K1  = (const float*)d_in[14]; const float* cb1 = (const float*)d_in[15];
    const float* K2  = (const float*)d_in[16]; const float* cb2 = (const float*)d_in[17];
    const float* K3  = (const float*)d_in[18]; const float* cb3 = (const float*)d_in[19];
    const float* Wxt = (const float*)d_in[20]; const float* bxt = (const float*)d_in[21];
    const float* Wf1 = (const float*)d_in[22]; const float* bf1 = (const float*)d_in[23];
    const float* Wf2 = (const float*)d_in[24]; const float* bf2 = (const float*)d_in[25];
    const float* Wo  = (const float*)d_in[26]; const float* bo  = (const float*)d_in[27];
    const int* srcp = ei;        // edge_index[0]
    const int* dstp = ei + NE;   // edge_index[1]

    float* ws = (float*)d_ws;
    float4* dt1 = (float4*)ws; ws += (size_t)NA * 4;   // dis*x          (3.2 MB)
    float4* dt2 = (float4*)ws; ws += (size_t)NA * 4;   // dis*out1       (3.2 MB)
    uint4*  dt3 = (uint4*)ws;  ws += (size_t)NA * 4;   // dis*out2 fp16  (3.2 MB)
    float* g     = ws; ws += NB * 16;
    float* gp1   = ws; ws += NB * 1024;
    float* gvec  = ws; ws += NB * 128;
    float* cx    = ws; ws += NB * 128;
    float* xf1   = ws; ws += NB * 1024;
    float* xf2   = ws; ws += NB * 512;
    __half* pool1 = (__half*)ws; ws += (size_t)NB * 32 * 331;   // fp16 (half used)
    __half* pool2t = (__half*)ws; ws += (size_t)NB * 64 * 108;  // fp16 [b][P][64]
    float* pool3 = ws; ws += (size_t)NB * 128 * 33;             // fp32 [b][33][128]
    __half* Wt2 = (__half*)ws; ws += 64 * 256 / 2;              // fp16 tap-major
    __half* Wt3 = (__half*)ws; ws += 128 * 512 / 2;             // fp16 tap-major
    int*   cnt    = (int*)ws; ws += NA;
    int*   rowptr = (int*)ws; ws += NA;
    int*   csr    = (int*)ws; ws += NE;               // compact CSR
    int*   gcursor= (int*)ws; ws += NBKT;
    unsigned* stage = (unsigned*)ws; ws += (size_t)NBKT * BKTCAP; // 16.8 MB

    dim3 blk(256);

    k_init<<<2048, blk, 0, stream>>>((unsigned*)g, gcursor, gvec, bg2, xf2, bf2,
                                     xf1, bf1, K2, K3, Wt2, Wt3);
    k_A<<<1512, blk, 0, stream>>>(srcp, dstp, gcursor, stage, tgt, K1, cb1, pool1);
    k_Bp<<<768, blk, 0, stream>>>(stage, gcursor, rowptr, cnt, csr, x, dt1,
                                  tgt, K1, cb1, pool1);
    // K_B: conv2 (512) || coop-gather1 (3125)
    k_B<<<512 + NGB, blk, 0, stream>>>(pool1, Wt2, cb2, pool2t,
                                       dt1, rowptr, cnt, csr, W1, b1, (float*)dt2);
    // K_C: conv3 N-split (1024) || coop-gather2 (3125)
    k_C<<<1024 + NGB, blk, 0, stream>>>(pool2t, Wt3, cb3, pool3,
                                        dt2, rowptr, cnt, csr, W2, b2, (unsigned*)dt3);
    // K_D: coop-gather3 (3125) || mean+Wxt (64)
    k_D<<<NGB + 64, blk, 0, stream>>>(dt3, rowptr, cnt, csr, W3, b3,
                                      batch, (unsigned*)g, pool3, Wxt, bxt, cx);

    // dense head (latency-hiding: >=512 blocks, 16-deep load batching)
    k_head_g<<<256, blk, 0, stream>>>(g, Wg1, bg1, gp1);
    k_gvec_ks<<<dim3(8, 64), blk, 0, stream>>>(gp1, Wg2, gvec);
    k_cat2<<<dim3(8, 64), blk, 0, stream>>>(gvec, cx, Wf1, xf1);
    k_xf2_ks<<<dim3(8, 64), blk, 0, stream>>>(xf1, Wf2, xf2);
    k_dense_out<<<4, blk, 0, stream>>>(xf2, Wo, bo, (float*)d_out);
}

// Round 11
// 401.475 us; speedup vs baseline: 1.1756x; 1.1756x over previous
//
#include <hip/hip_runtime.h>
#include <hip/hip_fp16.h>
#include <cstddef>

#define NA 200000
#define NE 3200000
#define NB 512
#define NBKT 256          // dst-range buckets
#define BKTN 782          // nodes per bucket
#define BKTCAP 16384      // stage capacity per bucket (exp 12500, sigma ~111)
#define NEPB 3200         // edges per pass-1 block (1000*3200 = NE)
#define NGB 3125          // gather blocks: 3125*64 = 200000 = NA exactly

// ---------------- fp16 helpers ----------------
typedef _Float16 hv2 __attribute__((ext_vector_type(2)));
typedef _Float16 half8 __attribute__((ext_vector_type(8)));
typedef float floatx4 __attribute__((ext_vector_type(4)));
union UH2 { unsigned u; __half2 h; hv2 v; };
__device__ __forceinline__ float4 h4f(unsigned a, unsigned b) {
    UH2 x, y; x.u = a; y.u = b;
    float2 fa = __half22float2(x.h), fb = __half22float2(y.h);
    return make_float4(fa.x, fa.y, fb.x, fb.y);
}
__device__ __forceinline__ unsigned f2h(float a, float b) {
    UH2 r; r.h = __float22half2_rn(make_float2(a, b));
    return r.u;
}

// -------- init: accumulator pre-init + weight repack to fp16 ---------------
__global__ void k_init(unsigned* g, int* gcursor,
                       float* gvec, const float* __restrict__ bg2,
                       float* xf2, const float* __restrict__ bf2,
                       float* xf1, const float* __restrict__ bf1,
                       const float* __restrict__ K2, const float* __restrict__ K3,
                       __half* __restrict__ Wt2, __half* __restrict__ Wt3) {
    int i = blockIdx.x * blockDim.x + threadIdx.x;
    if (i < NB * 16) g[i] = 0u;
    if (i < NBKT) gcursor[i] = i * BKTCAP;
    if (i < NB * 128) gvec[i] = bg2[i & 127];
    if (i < NB * 512) xf2[i] = bf2[i & 511];
    if (i < NB * 1024) xf1[i] = bf1[i & 1023];
    if (i < 64 * 32 * 8) {
        int o = i >> 8, rem = i & 255, c = rem >> 3, kk = rem & 7;
        Wt2[(o << 8) + (kk << 5) + c] = __float2half(K2[i]);
    }
    if (i < 128 * 64 * 8) {
        int o = i >> 9, rem = i & 511, c = rem >> 3, kk = rem & 7;
        Wt3[(o << 9) + (kk << 6) + c] = __float2half(K3[i]);
    }
}

// ------- conv1 device body (fp32 LDS/compute, fp16 output) -----------------
// PT=4: natural VGPR ~124. NO launch_bounds force: both attempts to pin the
// 64-VGPR bucket (R7 PT=2, R10 PT=1) made the allocator spill (6x traffic).
// Lever retired; conv1 long blocks are instead dispatched FIRST (LPT order).
template<int CIN, int COUT, int OBLK, int LIN, int PITCH, int POUT, int NTT>
__device__ __forceinline__ void dev_conv1(int b, int oy,
        const float* __restrict__ in, const float* __restrict__ Kw,
        const float* __restrict__ bias, __half* __restrict__ out,
        float* s_in) {
    constexpr int SPO = 256 / OBLK;
    constexpr int PT = (NTT < 4) ? NTT : 4;
    constexpr int NPASS = (NTT + PT - 1) / PT;
    for (int idx = threadIdx.x; idx < CIN * PITCH; idx += 256) s_in[idx] = 0.f;
    __syncthreads();
    for (int idx = threadIdx.x; idx < LIN * CIN; idx += 256) {
        int p = idx / CIN, c = idx - p * CIN;
        s_in[c * PITCH + p] = in[(size_t)b * (LIN * CIN) + idx];
    }
    __syncthreads();
    int ol = threadIdx.x / SPO;
    int s  = threadIdx.x - ol * SPO;
    int o  = oy * OBLK + ol;
    float bo = bias[o];
    const float* wrow = Kw + (size_t)o * CIN * 8;
    for (int pass = 0; pass < NPASS; pass++) {
        float acc[PT][12];
#pragma unroll
        for (int tt = 0; tt < PT; tt++)
#pragma unroll
            for (int j = 0; j < 12; j++) acc[tt][j] = 0.f;
        bool vld[PT]; int tgs[PT];
#pragma unroll
        for (int tt = 0; tt < PT; tt++) {
            int ta = pass * PT + tt;
            int tg = s + SPO * ta;
            tgs[tt] = tg;
            vld[tt] = (ta < NTT) && (4 * tg < POUT);
        }
        for (int i = 0; i < CIN; i++) {
            float wa[8];
            const float4* wp = (const float4*)(wrow + (size_t)i * 8);
            *(float4*)&wa[0] = wp[0];
            *(float4*)&wa[4] = wp[1];
#pragma unroll
            for (int tt = 0; tt < PT; tt++) {
                if (vld[tt]) {
                    const float4* xr = (const float4*)&s_in[i * PITCH + 12 * tgs[tt]];
                    float xa[20];
#pragma unroll
                    for (int q = 0; q < 5; q++) *(float4*)&xa[4 * q] = xr[q];
#pragma unroll
                    for (int j = 0; j < 12; j++) {
                        float sm = acc[tt][j];
#pragma unroll
                        for (int k = 0; k < 8; k++) sm = fmaf(xa[j + k], wa[k], sm);
                        acc[tt][j] = sm;
                    }
                }
            }
        }
#pragma unroll
        for (int tt = 0; tt < PT; tt++) {
            if (vld[tt]) {
#pragma unroll
                for (int p = 0; p < 4; p++) {
                    int P = 4 * tgs[tt] + p;
                    if (P < POUT) {
                        float m = fmaxf(fmaxf(acc[tt][3 * p], acc[tt][3 * p + 1]), acc[tt][3 * p + 2]);
                        out[((size_t)b * COUT + o) * POUT + P] = __float2half(fmaxf(m + bo, 0.f));
                    }
                }
            }
        }
    }
}

// ======================= MFMA conv2 ========================================
__device__ __forceinline__ void dev_conv2_mfma(int b,
        const __half* __restrict__ pool1, const __half* __restrict__ Wt2,
        const float* __restrict__ cb2, __half* __restrict__ pool2t,
        char* smem) {
    __half* sT   = (__half*)smem;   // [344][40] halves = 27520 B
    __half* outS = (__half*)smem;   // [336][68] halves = 45696 B (overlays sT)
    const __half* inp = pool1 + (size_t)b * (32 * 331);
    for (int idx = threadIdx.x; idx < 32 * 331; idx += 256) {
        int c = idx / 331;
        int p = idx - c * 331;
        sT[p * 40 + c] = inp[idx];              // LDS transpose (2B scattered)
    }
    __syncthreads();
    int lane = threadIdx.x & 63, wv = threadIdx.x >> 6;
    int l15 = lane & 15, lg = lane >> 4;
    int mtBeg = wv * 5;
    int nmt = (wv == 3) ? 6 : 5;
    const floatx4 FZ = {0.f, 0.f, 0.f, 0.f};
    floatx4 acc[6][4];
#pragma unroll
    for (int mi = 0; mi < 6; mi++)
#pragma unroll
        for (int nt = 0; nt < 4; nt++) acc[mi][nt] = FZ;
    const half8* WB = (const half8*)Wt2;
    for (int s = 0; s < 8; s++) {
        half8 bfr[4];
#pragma unroll
        for (int nt = 0; nt < 4; nt++)
            bfr[nt] = WB[(nt * 16 + l15) * 32 + s * 4 + lg];
        half8 afr[6];
#pragma unroll
        for (int mi = 0; mi < 6; mi++) {
            if (mi < nmt) {
                int row = (mtBeg + mi) * 16 + l15 + s;
                afr[mi] = *(const half8*)(sT + row * 40 + lg * 8);
            }
        }
#pragma unroll
        for (int mi = 0; mi < 6; mi++) {
            if (mi < nmt) {
#pragma unroll
                for (int nt = 0; nt < 4; nt++)
                    acc[mi][nt] = __builtin_amdgcn_mfma_f32_16x16x32_f16(
                        afr[mi], bfr[nt], acc[mi][nt], 0, 0, 0);
            }
        }
    }
    __syncthreads();                              // sT reads done; overlay outS
    float bo[4];
#pragma unroll
    for (int nt = 0; nt < 4; nt++) bo[nt] = cb2[nt * 16 + l15];
#pragma unroll
    for (int mi = 0; mi < 6; mi++) {
        if (mi < nmt) {
#pragma unroll
            for (int nt = 0; nt < 4; nt++) {
                int o = nt * 16 + l15;
#pragma unroll
                for (int r = 0; r < 4; r++) {
                    int p = (mtBeg + mi) * 16 + lg * 4 + r;
                    float v = fmaxf(acc[mi][nt][r] + bo[nt], 0.f);
                    outS[p * 68 + o] = __float2half(v);
                }
            }
        }
    }
    __syncthreads();
    __half* op = pool2t + (size_t)b * (108 * 64);
    for (int idx = threadIdx.x; idx < 108 * 64; idx += 256) {
        int P = idx >> 6, o = idx & 63;
        float v0 = __half2float(outS[(3 * P) * 68 + o]);
        float v1 = __half2float(outS[(3 * P + 1) * 68 + o]);
        float v2 = __half2float(outS[(3 * P + 2) * 68 + o]);
        op[idx] = __float2half(fmaxf(fmaxf(v0, v1), v2));   // [b][P][o]
    }
}

// ======================= MFMA conv3 (N-split halves) =======================
// acc[2][4] (32 VGPR): fused kernel's natural live set fits the <=64 bucket
// so launch_bounds(256,8) is SAFE here (verified: k_C Occ 50-65%, no spill).
__device__ __forceinline__ void dev_conv3_mfma(int b, int nh,
        const __half* __restrict__ pool2t, const __half* __restrict__ Wt3,
        const float* __restrict__ cb3, float* __restrict__ pool3,
        char* smem) {
    __half* sT  = (__half*)smem;   // [120][72] halves = 17280 B
    float* outS = (float*)smem;    // [48][68] fp32 = 13056 B (overlays sT)
    const uint4* inp = (const uint4*)(pool2t + (size_t)b * (108 * 64));
    for (int t = threadIdx.x; t < 108 * 8; t += 256) {
        int r = t >> 3, s8 = t & 7;
        *(uint4*)(sT + r * 72 + s8 * 8) = inp[t];
    }
    __syncthreads();
    int lane = threadIdx.x & 63, wv = threadIdx.x >> 6;
    int l15 = lane & 15, lg = lane >> 4;
    int mtBeg = wv * 2;
    int nmt = (wv == 3) ? 1 : 2;
    const floatx4 FZ = {0.f, 0.f, 0.f, 0.f};
    floatx4 acc[2][4];
#pragma unroll
    for (int mi = 0; mi < 2; mi++)
#pragma unroll
        for (int nt = 0; nt < 4; nt++) acc[mi][nt] = FZ;
    const half8* WB = (const half8*)Wt3;
    for (int s = 0; s < 16; s++) {
        half8 afr[2];
#pragma unroll
        for (int mi = 0; mi < 2; mi++) {
            if (mi < nmt) {
                int row = (mtBeg + mi) * 16 + l15 + (s >> 1);
                afr[mi] = *(const half8*)(sT + row * 72 + (s & 1) * 32 + lg * 8);
            }
        }
#pragma unroll
        for (int nt = 0; nt < 4; nt++) {
            half8 bfr = WB[((nh * 4 + nt) * 16 + l15) * 64 + s * 4 + lg];
            acc[0][nt] = __builtin_amdgcn_mfma_f32_16x16x32_f16(
                afr[0], bfr, acc[0][nt], 0, 0, 0);
            if (nmt > 1)
                acc[1][nt] = __builtin_amdgcn_mfma_f32_16x16x32_f16(
                    afr[1], bfr, acc[1][nt], 0, 0, 0);
        }
    }
    __syncthreads();                              // MFMA done; sT dead
    float bo[4];
#pragma unroll
    for (int nt = 0; nt < 4; nt++) bo[nt] = cb3[(nh * 4 + nt) * 16 + l15];
    float* op = pool3 + (size_t)b * (33 * 128);
    for (int pp = 0; pp < 3; pp++) {
        int t0 = 3 * pp;
#pragma unroll
        for (int mi = 0; mi < 2; mi++) {
            int tile = mtBeg + mi;
            if (mi < nmt && tile >= t0 && tile < t0 + 3) {
#pragma unroll
                for (int nt = 0; nt < 4; nt++) {
                    int ol = nt * 16 + l15;
#pragma unroll
                    for (int r = 0; r < 4; r++) {
                        int p = tile * 16 + lg * 4 + r;
                        if (p < 100)
                            outS[(p - 48 * pp) * 68 + ol] =
                                fmaxf(acc[mi][nt][r] + bo[nt], 0.f);
                    }
                }
            }
        }
        __syncthreads();
        int nP = (pp == 2) ? 1 : 16;
        for (int idx = threadIdx.x; idx < nP * 64; idx += 256) {
            int Pl = idx >> 6, ol = idx & 63;
            int P = 16 * pp + Pl;
            int p = 3 * P - 48 * pp;
            float v0 = outS[p * 68 + ol];
            float v1 = outS[(p + 1) * 68 + ol];
            float v2 = outS[(p + 2) * 68 + ol];
            op[P * 128 + (nh << 6) + ol] = fmaxf(fmaxf(v0, v1), v2);
        }
        __syncthreads();
    }
}

// -------- K_A: conv1 oy=0 (512, FIRST: long blocks) || pass1 binning (1000)
__global__ __launch_bounds__(256) void k_A(
        const int* __restrict__ src, const int* __restrict__ dst,
        int* __restrict__ gcursor, unsigned* __restrict__ stage,
        const float* __restrict__ tgt, const float* __restrict__ K1,
        const float* __restrict__ cb1, __half* __restrict__ pool1) {
    __shared__ __align__(16) char smem[20160];   // conv1 s_in OR sort arrays
    int bx = blockIdx.x;
    if (bx < 512) {                               // LPT: long conv1 first
        dev_conv1<5, 32, 16, 1000, 1008, 331, 6>(bx, 0, tgt, K1, cb1,
                                                 pool1, (float*)smem);
        return;
    }
    int* hcnt  = (int*)smem;                 // [256] count -> scan -> cursor
    int* hbase = hcnt + 256;                 // [256] global bucket base
    int* lbase = hbase + 256;                // [256] local bucket base
    unsigned* sbuf = (unsigned*)(lbase + 256);      // [3200] sorted entries
    unsigned char* sbkt = (unsigned char*)(sbuf + NEPB); // [3200] bucket ids
    int t = threadIdx.x;
    int e0 = (bx - 512) * NEPB;
    hcnt[t] = 0;
    __syncthreads();
    const int4* d4 = (const int4*)(dst + e0);
    for (int i = t; i < NEPB / 4; i += 256) {
        int4 d = d4[i];
        atomicAdd(&hcnt[d.x / BKTN], 1);
        atomicAdd(&hcnt[d.y / BKTN], 1);
        atomicAdd(&hcnt[d.z / BKTN], 1);
        atomicAdd(&hcnt[d.w / BKTN], 1);
    }
    __syncthreads();
    int myc = hcnt[t];
    hbase[t] = atomicAdd(&gcursor[t], myc);
    __syncthreads();
    // in-place inclusive scan of hcnt (Hillis-Steele)
#pragma unroll
    for (int off = 1; off < 256; off <<= 1) {
        int u = (t >= off) ? hcnt[t - off] : 0;
        __syncthreads();
        hcnt[t] += u;
        __syncthreads();
    }
    lbase[t] = hcnt[t] - myc;   // exclusive base
    hcnt[t] = 0;                // reuse as per-bucket cursor
    __syncthreads();
    const int4* s4 = (const int4*)(src + e0);
    for (int i = t; i < NEPB / 4; i += 256) {
        int4 d = d4[i];
        int4 s = s4[i];
        int ds[4] = {d.x, d.y, d.z, d.w};
        int ss[4] = {s.x, s.y, s.z, s.w};
#pragma unroll
        for (int j = 0; j < 4; j++) {
            int bkt = ds[j] / BKTN;
            int dloc = ds[j] - bkt * BKTN;
            int k = atomicAdd(&hcnt[bkt], 1);
            int pos = lbase[bkt] + k;
            sbuf[pos] = ((unsigned)dloc << 18) | (unsigned)ss[j];
            sbkt[pos] = (unsigned char)bkt;
        }
    }
    __syncthreads();
    // coalesced copy-out: consecutive i -> consecutive stage addresses
    for (int i = t; i < NEPB; i += 256) {
        unsigned v = sbuf[i];
        int bkt = sbkt[i];
        stage[hbase[bkt] + (i - lbase[bkt])] = v;
    }
}

// -------- K_Bp: conv1 oy=1 (512, FIRST) || pass2 (256) ---------------------
__global__ __launch_bounds__(256) void k_Bp(
        const unsigned* __restrict__ stage, const int* __restrict__ gcursor,
        int* __restrict__ rowptr, int* __restrict__ cnt, int* __restrict__ csr,
        const float* __restrict__ x, float4* __restrict__ dt1,
        const float* __restrict__ tgt, const float* __restrict__ K1,
        const float* __restrict__ cb1, __half* __restrict__ pool1) {
    __shared__ __align__(16) char smem[20160];   // conv1 s_in OR pass2 arrays
    __shared__ int sbase;
    int bx = blockIdx.x;
    if (bx < 512) {                               // LPT: long conv1 first
        dev_conv1<5, 32, 16, 1000, 1008, 331, 6>(bx, 1, tgt, K1, cb1,
                                                 pool1, (float*)smem);
        return;
    }
    int* lcnt    = (int*)smem;       // [782]
    int* lpos    = lcnt + BKTN;      // [782]
    int* partial = lpos + BKTN;      // [256]
    int t = threadIdx.x;
    int bkt = bx - 512;
    int tot = gcursor[t] - t * BKTCAP;
    partial[t] = tot;
    __syncthreads();
#pragma unroll
    for (int off = 1; off < 256; off <<= 1) {
        int u = (t >= off) ? partial[t - off] : 0;
        __syncthreads();
        partial[t] += u;
        __syncthreads();
    }
    if (t == 0) sbase = (bkt == 0) ? 0 : partial[bkt - 1];
    __syncthreads();
    int base = sbase;
    int n0 = bkt * BKTN;
    int ncnt = (NA - n0 < BKTN) ? (NA - n0) : BKTN;
    int eBeg = bkt * BKTCAP;
    int eCnt = gcursor[bkt] - eBeg;
    for (int i = t; i < BKTN; i += 256) lcnt[i] = 0;
    __syncthreads();
    for (int i = t; i < eCnt; i += 256)
        atomicAdd(&lcnt[stage[eBeg + i] >> 18], 1);
    __syncthreads();
    int mysum = 0;
#pragma unroll
    for (int j = 0; j < 4; j++) {
        int node = 4 * t + j;
        if (node < ncnt) mysum += lcnt[node];
    }
    partial[t] = mysum;
    __syncthreads();
#pragma unroll
    for (int off = 1; off < 256; off <<= 1) {
        int u = (t >= off) ? partial[t - off] : 0;
        __syncthreads();
        partial[t] += u;
        __syncthreads();
    }
    int running = partial[t] - mysum;
#pragma unroll
    for (int j = 0; j < 4; j++) {
        int node = 4 * t + j;
        if (node < ncnt) {
            lpos[node] = running;
            rowptr[n0 + node] = base + running;
            cnt[n0 + node] = lcnt[node];
            running += lcnt[node];
        }
    }
    __syncthreads();
    for (int i = t; i < eCnt; i += 256) {
        unsigned v = stage[eBeg + i];
        int dloc = v >> 18;
        int s = v & 0x3FFFF;
        int k = atomicAdd(&lpos[dloc], 1);
        csr[base + k] = s;
    }
    for (int i = t; i < ncnt; i += 256) {
        int n = n0 + i;
        float4 p = ((const float4*)x)[n];
        float dv = rsqrtf((float)lcnt[i] + 1.0f);
        dt1[n] = make_float4(dv * p.x, dv * p.y, dv * p.z, dv * p.w);
    }
}

// -------- K_B: conv2 MFMA (512) || coop-gather1+W1 -> dt2 (3125) -----------
// 4 lanes/node: lane sub loads neighbors e=sub,sub+4,..., butterfly shfl_xor
// combines; lane sub computes output f=sub; 4B coalesced write.
__global__ __launch_bounds__(256) void k_B(
        const __half* __restrict__ pool1, const __half* __restrict__ Wt2,
        const float* __restrict__ cb2, __half* __restrict__ pool2t,
        const float4* __restrict__ dt1, const int* __restrict__ rowptr,
        const int* __restrict__ cnt, const int* __restrict__ csr,
        const float* __restrict__ W1, const float* __restrict__ b1,
        float* __restrict__ dt2f) {
    __shared__ __align__(16) char smem[45696];
    int bx = blockIdx.x;
    if (bx < 512) {
        dev_conv2_mfma(bx, pool1, Wt2, cb2, pool2t, smem);
        return;
    }
    __shared__ float sW[16];
    if (threadIdx.x < 16) sW[threadIdx.x] = W1[threadIdx.x];
    __syncthreads();
    int n   = (bx - 512) * 64 + (threadIdx.x >> 2);   // always < NA
    int sub = threadIdx.x & 3;
    int cn = cnt[n];
    float dv = rsqrtf((float)cn + 1.0f);
    const int* row = csr + rowptr[n];
    float4 selfv = dt1[n];                            // broadcast load
    float4 acc = make_float4(0.f, 0.f, 0.f, 0.f);
    if (sub == 0) acc = selfv;
    int e = sub;
    for (; e + 4 < cn; e += 8) {                      // 2 independent loads
        float4 v0 = dt1[row[e]];
        float4 v1 = dt1[row[e + 4]];
        acc.x += v0.x + v1.x; acc.y += v0.y + v1.y;
        acc.z += v0.z + v1.z; acc.w += v0.w + v1.w;
    }
    if (e < cn) {
        float4 v = dt1[row[e]];
        acc.x += v.x; acc.y += v.y; acc.z += v.z; acc.w += v.w;
    }
    // butterfly over the 4-lane group
    acc.x += __shfl_xor(acc.x, 1); acc.y += __shfl_xor(acc.y, 1);
    acc.z += __shfl_xor(acc.z, 1); acc.w += __shfl_xor(acc.w, 1);
    acc.x += __shfl_xor(acc.x, 2); acc.y += __shfl_xor(acc.y, 2);
    acc.z += __shfl_xor(acc.z, 2); acc.w += __shfl_xor(acc.w, 2);
    float a[4] = {acc.x, acc.y, acc.z, acc.w};
    float s = 0.f;
#pragma unroll
    for (int k = 0; k < 4; k++) s = fmaf(a[k], sW[k * 4 + sub], s);
    float o = dv * fmaxf(fmaf(dv, s, b1[sub]), 0.f);  // dt2 = dv*relu(...)
    dt2f[(size_t)n * 4 + sub] = o;
}

// -------- K_C: conv3 N-split (1024) || coop-gather2+W2 -> dt3 (3125) -------
// launch_bounds(256,8): fused live set ~32 regs, no spill risk (verified).
__global__ __launch_bounds__(256, 8) void k_C(
        const __half* __restrict__ pool2t, const __half* __restrict__ Wt3,
        const float* __restrict__ cb3, float* __restrict__ pool3,
        const float4* __restrict__ dt2, const int* __restrict__ rowptr,
        const int* __restrict__ cnt, const int* __restrict__ csr,
        const float* __restrict__ W2, const float* __restrict__ b2,
        unsigned* __restrict__ dt3u) {
    __shared__ __align__(16) char smem[17280];
    int bx = blockIdx.x;
    if (bx < 1024) {
        dev_conv3_mfma(bx & 511, bx >> 9, pool2t, Wt3, cb3, pool3, smem);
        return;
    }
    __shared__ float sW[32];
    if (threadIdx.x < 32) sW[threadIdx.x] = W2[threadIdx.x];
    __syncthreads();
    int n   = (bx - 1024) * 64 + (threadIdx.x >> 2);
    int sub = threadIdx.x & 3;
    int cn = cnt[n];
    float dv = rsqrtf((float)cn + 1.0f);
    const int* row = csr + rowptr[n];
    float4 selfv = dt2[n];
    float4 acc = make_float4(0.f, 0.f, 0.f, 0.f);
    if (sub == 0) acc = selfv;
    int e = sub;
    for (; e + 4 < cn; e += 8) {
        float4 v0 = dt2[row[e]];
        float4 v1 = dt2[row[e + 4]];
        acc.x += v0.x + v1.x; acc.y += v0.y + v1.y;
        acc.z += v0.z + v1.z; acc.w += v0.w + v1.w;
    }
    if (e < cn) {
        float4 v = dt2[row[e]];
        acc.x += v.x; acc.y += v.y; acc.z += v.z; acc.w += v.w;
    }
    acc.x += __shfl_xor(acc.x, 1); acc.y += __shfl_xor(acc.y, 1);
    acc.z += __shfl_xor(acc.z, 1); acc.w += __shfl_xor(acc.w, 1);
    acc.x += __shfl_xor(acc.x, 2); acc.y += __shfl_xor(acc.y, 2);
    acc.z += __shfl_xor(acc.z, 2); acc.w += __shfl_xor(acc.w, 2);
    float a[4] = {acc.x, acc.y, acc.z, acc.w};
    int f0 = 2 * sub;
    float s0 = 0.f, s1 = 0.f;
#pragma unroll
    for (int k = 0; k < 4; k++) {
        s0 = fmaf(a[k], sW[k * 8 + f0], s0);
        s1 = fmaf(a[k], sW[k * 8 + f0 + 1], s1);
    }
    float o0 = dv * fmaxf(fmaf(dv, s0, b2[f0]), 0.f);
    float o1 = dv * fmaxf(fmaf(dv, s1, b2[f0 + 1]), 0.f);
    dt3u[(size_t)n * 4 + sub] = f2h(o0, o1);
}

// -------- K_D: coop-gather3(fp16)+W3+segmax (3125) || mean+Wxt (64) --------
__global__ __launch_bounds__(256) void k_D(
        const uint4* __restrict__ dt3, const int* __restrict__ rowptr,
        const int* __restrict__ cnt, const int* __restrict__ csr,
        const float* __restrict__ W3, const float* __restrict__ b3,
        const int* __restrict__ batch, unsigned* __restrict__ g,
        const float* __restrict__ pool3, const float* __restrict__ Wxt,
        const float* __restrict__ bxt, float* __restrict__ cx) {
    int bx = blockIdx.x;
    if (bx >= NGB) {
        __shared__ float sa[8 * 128];
        int b0 = (bx - NGB) * 8;
        for (int t = threadIdx.x; t < 8 * 128; t += 256) {
            int gg = t >> 7, k = t & 127;
            // pool3 layout [b][P=33][o=128]; lanes read consecutive o
            const float* r = pool3 + (size_t)(b0 + gg) * (33 * 128) + k;
            float s = 0.f;
#pragma unroll
            for (int p = 0; p < 33; p++) s += r[p * 128];
            sa[t] = s * (1.f / 33.f);
        }
        __syncthreads();
        int j = threadIdx.x;
        if (j >= 128) return;
        float bj = bxt[j];
        float acc[8];
#pragma unroll
        for (int gg = 0; gg < 8; gg++) acc[gg] = bj;
#pragma unroll 4
        for (int k = 0; k < 128; k++) {
            float w = Wxt[(size_t)k * 128 + j];
#pragma unroll
            for (int gg = 0; gg < 8; gg++) acc[gg] = fmaf(sa[gg * 128 + k], w, acc[gg]);
        }
#pragma unroll
        for (int gg = 0; gg < 8; gg++)
            cx[(size_t)(b0 + gg) * 128 + j] = fmaxf(acc[gg], 0.f);
        return;
    }
    __shared__ float sW[128];
    __shared__ unsigned sg[32];
    __shared__ int sbmin;
    if (threadIdx.x < 128) sW[threadIdx.x] = W3[threadIdx.x];
    if (threadIdx.x < 32) sg[threadIdx.x] = 0u;
    if (threadIdx.x == 0) sbmin = batch[bx * 64];
    __syncthreads();
    int n   = bx * 64 + (threadIdx.x >> 2);          // always < NA
    int sub = threadIdx.x & 3;
    int cn = cnt[n];
    float dv = rsqrtf((float)cn + 1.0f);
    const int* row = csr + rowptr[n];
    uint4 sv = dt3[n];
    float4 slo = h4f(sv.x, sv.y), shi = h4f(sv.z, sv.w);
    float a0 = 0.f, a1 = 0.f, a2 = 0.f, a3 = 0.f;
    float a4 = 0.f, a5 = 0.f, a6 = 0.f, a7 = 0.f;
    if (sub == 0) {
        a0 = slo.x; a1 = slo.y; a2 = slo.z; a3 = slo.w;
        a4 = shi.x; a5 = shi.y; a6 = shi.z; a7 = shi.w;
    }
    int e = sub;
    for (; e + 4 < cn; e += 8) {
        uint4 p0 = dt3[row[e]], p1 = dt3[row[e + 4]];
        float4 l0 = h4f(p0.x, p0.y), h0 = h4f(p0.z, p0.w);
        float4 l1 = h4f(p1.x, p1.y), h1 = h4f(p1.z, p1.w);
        a0 += l0.x + l1.x; a1 += l0.y + l1.y;
        a2 += l0.z + l1.z; a3 += l0.w + l1.w;
        a4 += h0.x + h1.x; a5 += h0.y + h1.y;
        a6 += h0.z + h1.z; a7 += h0.w + h1.w;
    }
    if (e < cn) {
        uint4 p = dt3[row[e]];
        float4 l = h4f(p.x, p.y), h = h4f(p.z, p.w);
        a0 += l.x; a1 += l.y; a2 += l.z; a3 += l.w;
        a4 += h.x; a5 += h.y; a6 += h.z; a7 += h.w;
    }
    a0 += __shfl_xor(a0, 1); a1 += __shfl_xor(a1, 1);
    a2 += __shfl_xor(a2, 1); a3 += __shfl_xor(a3, 1);
    a4 += __shfl_xor(a4, 1); a5 += __shfl_xor(a5, 1);
    a6 += __shfl_xor(a6, 1); a7 += __shfl_xor(a7, 1);
    a0 += __shfl_xor(a0, 2); a1 += __shfl_xor(a1, 2);
    a2 += __shfl_xor(a2, 2); a3 += __shfl_xor(a3, 2);
    a4 += __shfl_xor(a4, 2); a5 += __shfl_xor(a5, 2);
    a6 += __shfl_xor(a6, 2); a7 += __shfl_xor(a7, 2);
    float af[8] = {a0, a1, a2, a3, a4, a5, a6, a7};
    int rb = batch[n] - sbmin;
    if (rb > 1) rb = 1;
#pragma unroll
    for (int j = 0; j < 4; j++) {
        int f = sub * 4 + j;
        float s = 0.f;
#pragma unroll
        for (int k = 0; k < 8; k++) s = fmaf(af[k], sW[k * 16 + f], s);
        float r = fmaxf(fmaf(dv, s, b3[f]), 0.f);
        atomicMax(&sg[rb * 16 + f], __float_as_uint(r));
    }
    __syncthreads();
    if (threadIdx.x < 32) {
        unsigned v = sg[threadIdx.x];
        int rb2 = threadIdx.x >> 4, f = threadIdx.x & 15;
        int bbn = sbmin + rb2;
        if (v != 0u && bbn < NB) atomicMax(&g[bbn * 16 + f], v);
    }
}

// -------- head: g@Wg1 -> gp1 (relu), 256 blocks ----------------------------
__global__ __launch_bounds__(256) void k_head_g(
        const float* __restrict__ g, const float* __restrict__ Wg1,
        const float* __restrict__ bg1, float* __restrict__ gp1) {
    __shared__ float sa[8 * 16];
    int bx = blockIdx.x;
    int b0 = (bx >> 2) * 8;
    if (threadIdx.x < 128)
        sa[threadIdx.x] = g[b0 * 16 + threadIdx.x];
    __syncthreads();
    int j = (bx & 3) * 256 + threadIdx.x;
    float bj = bg1[j];
    float acc[8];
#pragma unroll
    for (int gg = 0; gg < 8; gg++) acc[gg] = bj;
#pragma unroll
    for (int k = 0; k < 16; k++) {
        float w = Wg1[(size_t)k * 1024 + j];
#pragma unroll
        for (int gg = 0; gg < 8; gg++) acc[gg] = fmaf(sa[gg * 16 + k], w, acc[gg]);
    }
#pragma unroll
    for (int gg = 0; gg < 8; gg++)
        gp1[(size_t)(b0 + gg) * 1024 + j] = fmaxf(acc[gg], 0.f);
}

// -------- gvec += (gp1 K-slice)@Wg2 ; grid (8,64), 16-deep batching --------
__global__ __launch_bounds__(256) void k_gvec_ks(
        const float* __restrict__ gp1, const float* __restrict__ Wg2,
        float* __restrict__ gvec) {
    __shared__ float sa[8 * 128];
    int k0 = blockIdx.x * 128;
    int b0 = blockIdx.y * 8;
    for (int t = threadIdx.x; t < 8 * 128; t += 256) {
        int gg = t >> 7, k = t & 127;
        sa[t] = gp1[(size_t)(b0 + gg) * 1024 + k0 + k];
    }
    __syncthreads();
    int j  = threadIdx.x & 127;
    int kh = (threadIdx.x >> 7) * 64;            // 0 or 64
    const float* Wp = Wg2 + (size_t)(k0 + kh) * 128 + j;
    float acc[8];
#pragma unroll
    for (int gg = 0; gg < 8; gg++) acc[gg] = 0.f;
    for (int k = 0; k < 64; k += 16) {
        float w[16];
#pragma unroll
        for (int u = 0; u < 16; u++) w[u] = Wp[(size_t)(k + u) * 128];
#pragma unroll
        for (int u = 0; u < 16; u++) {
#pragma unroll
            for (int gg = 0; gg < 8; gg++)
                acc[gg] = fmaf(sa[gg * 128 + kh + k + u], w[u], acc[gg]);
        }
    }
#pragma unroll
    for (int gg = 0; gg < 8; gg++)
        atomicAdd(&gvec[(size_t)(b0 + gg) * 128 + j], acc[gg]);
}

// -------- xf1 += ([gvec|cx] K-half)@Wf1 ; grid (8,64): 4j x 2kh ------------
__global__ __launch_bounds__(256) void k_cat2(
        const float* __restrict__ gvec, const float* __restrict__ cx,
        const float* __restrict__ Wf1, float* __restrict__ xf1) {
    __shared__ float sa[8 * 128];
    int jx = blockIdx.x & 3;
    int kh = blockIdx.x >> 2;                    // 0: gvec rows, 1: cx rows
    int b0 = blockIdx.y * 8;
    const float* A = kh ? cx : gvec;
    for (int t = threadIdx.x; t < 8 * 128; t += 256) {
        int gg = t >> 7, k = t & 127;
        sa[t] = A[(size_t)(b0 + gg) * 128 + k];
    }
    __syncthreads();
    int j = jx * 256 + threadIdx.x;
    const float* Wp = Wf1 + (size_t)(kh * 128) * 1024 + j;
    float acc[8];
#pragma unroll
    for (int gg = 0; gg < 8; gg++) acc[gg] = 0.f;
    for (int k = 0; k < 128; k += 16) {
        float w[16];
#pragma unroll
        for (int u = 0; u < 16; u++) w[u] = Wp[(size_t)(k + u) * 1024];
#pragma unroll
        for (int u = 0; u < 16; u++) {
#pragma unroll
            for (int gg = 0; gg < 8; gg++)
                acc[gg] = fmaf(sa[gg * 128 + k + u], w[u], acc[gg]);
        }
    }
#pragma unroll
    for (int gg = 0; gg < 8; gg++)
        atomicAdd(&xf1[(size_t)(b0 + gg) * 1024 + j], acc[gg]);
}

// -------- xf2 += relu(xf1 K-slice)@Wf2 ; grid (8,64): 2j x 4kc -------------
__global__ __launch_bounds__(256) void k_xf2_ks(
        const float* __restrict__ xf1, const float* __restrict__ Wf2,
        float* __restrict__ xf2) {
    __shared__ float sa[8 * 256];
    int jb = blockIdx.x & 1;
    int k0 = (blockIdx.x >> 1) * 256;
    int b0 = blockIdx.y * 8;
    for (int t = threadIdx.x; t < 8 * 256; t += 256) {
        int gg = t >> 8, k = t & 255;
        sa[t] = fmaxf(xf1[(size_t)(b0 + gg) * 1024 + k0 + k], 0.f);  // deferred relu
    }
    __syncthreads();
    int j = jb * 256 + threadIdx.x;
    const float* Wp = Wf2 + (size_t)k0 * 512 + j;
    float acc[8];
#pragma unroll
    for (int gg = 0; gg < 8; gg++) acc[gg] = 0.f;
    for (int k = 0; k < 256; k += 16) {
        float w[16];
#pragma unroll
        for (int u = 0; u < 16; u++) w[u] = Wp[(size_t)(k + u) * 512];
#pragma unroll
        for (int u = 0; u < 16; u++) {
#pragma unroll
            for (int gg = 0; gg < 8; gg++)
                acc[gg] = fmaf(sa[gg * 256 + k + u], w[u], acc[gg]);
        }
    }
#pragma unroll
    for (int gg = 0; gg < 8; gg++)
        atomicAdd(&xf2[(size_t)(b0 + gg) * 512 + j], acc[gg]);
}

// final 512->2 layer; applies the deferred relu on xf2; float4 A-loads
__global__ __launch_bounds__(256) void k_dense_out(
        const float* __restrict__ A, const float* __restrict__ W,
        const float* __restrict__ bias, float* __restrict__ out) {
    int idx = blockIdx.x * 256 + threadIdx.x;
    if (idx >= NB * 2) return;
    int b = idx >> 1, j = idx & 1;
    float s = bias[j];
    const float4* A4 = (const float4*)(A + (size_t)b * 512);
    for (int k4 = 0; k4 < 128; k4 += 8) {
        float4 av[8];
#pragma unroll
        for (int u = 0; u < 8; u++) av[u] = A4[k4 + u];
#pragma unroll
        for (int u = 0; u < 8; u++) {
            int kb = (k4 + u) * 4;
            s = fmaf(fmaxf(av[u].x, 0.f), W[(kb + 0) * 2 + j], s);
            s = fmaf(fmaxf(av[u].y, 0.f), W[(kb + 1) * 2 + j], s);
            s = fmaf(fmaxf(av[u].z, 0.f), W[(kb + 2) * 2 + j], s);
            s = fmaf(fmaxf(av[u].w, 0.f), W[(kb + 3) * 2 + j], s);
        }
    }
    out[idx] = s;
}

extern "C" void kernel_launch(void* const* d_in, const int* in_sizes, int n_in,
                              void* d_out, int out_size, void* d_ws, size_t ws_size,
                              hipStream_t stream) {
    (void)in_sizes; (void)n_in; (void)out_size; (void)ws_size;
    const float* x   = (const float*)d_in[0];
    const int*  ei   = (const int*)d_in[1];
    const int*  batch= (const int*)d_in[2];
    const float* tgt = (const float*)d_in[3];
    const float* W1  = (const float*)d_in[4];  const float* b1  = (const float*)d_in[5];
    const float* W2  = (const float*)d_in[6];  const float* b2  = (const float*)d_in[7];
    const float* W3  = (const float*)d_in[8];  const float* b3  = (const float*)d_in[9];
    const float* Wg1 = (const float*)d_in[10]; const float* bg1 = (const float*)d_in[11];
    const float* Wg2 = (const float*)d_in[12]; const float* bg2 = (const float*)d_in[13];
    const float* K1  = (const float*)d_in[14]; const float* cb1 = (const float*)d_in[15];
    const float* K2  = (const float*)d_in[16]; const float* cb2 = (const float*)d_in[17];
    const float* K3  = (const float*)d_in[18]; const float* cb3 = (const float*)d_in[19];
    const float* Wxt = (const float*)d_in[20]; const float* bxt = (const float*)d_in[21];
    const float* Wf1 = (const float*)d_in[22]; const float* bf1 = (const float*)d_in[23];
    const float* Wf2 = (const float*)d_in[24]; const float* bf2 = (const float*)d_in[25];
    const float* Wo  = (const float*)d_in[26]; const float* bo  = (const float*)d_in[27];
    const int* srcp = ei;        // edge_index[0]
    const int* dstp = ei + NE;   // edge_index[1]

    float* ws = (float*)d_ws;
    float4* dt1 = (float4*)ws; ws += (size_t)NA * 4;   // dis*x          (3.2 MB)
    float4* dt2 = (float4*)ws; ws += (size_t)NA * 4;   // dis*out1       (3.2 MB)
    uint4*  dt3 = (uint4*)ws;  ws += (size_t)NA * 4;   // dis*out2 fp16  (3.2 MB)
    float* g     = ws; ws += NB * 16;
    float* gp1   = ws; ws += NB * 1024;
    float* gvec  = ws; ws += NB * 128;
    float* cx    = ws; ws += NB * 128;
    float* xf1   = ws; ws += NB * 1024;
    float* xf2   = ws; ws += NB * 512;
    __half* pool1 = (__half*)ws; ws += (size_t)NB * 32 * 331;   // fp16 (half used)
    __half* pool2t = (__half*)ws; ws += (size_t)NB * 64 * 108;  // fp16 [b][P][64]
    float* pool3 = ws; ws += (size_t)NB * 128 * 33;             // fp32 [b][33][128]
    __half* Wt2 = (__half*)ws; ws += 64 * 256 / 2;              // fp16 tap-major
    __half* Wt3 = (__half*)ws; ws += 128 * 512 / 2;             // fp16 tap-major
    int*   cnt    = (int*)ws; ws += NA;
    int*   rowptr = (int*)ws; ws += NA;
    int*   csr    = (int*)ws; ws += NE;               // compact CSR
    int*   gcursor= (int*)ws; ws += NBKT;
    unsigned* stage = (unsigned*)ws; ws += (size_t)NBKT * BKTCAP; // 16.8 MB

    dim3 blk(256);

    k_init<<<2048, blk, 0, stream>>>((unsigned*)g, gcursor, gvec, bg2, xf2, bf2,
                                     xf1, bf1, K2, K3, Wt2, Wt3);
    // K_A: conv1 oy=0 (512 first, LPT) || pass1 binning (1000)
    k_A<<<1512, blk, 0, stream>>>(srcp, dstp, gcursor, stage, tgt, K1, cb1, pool1);
    // K_Bp: conv1 oy=1 (512 first, LPT) || pass2 (256)
    k_Bp<<<768, blk, 0, stream>>>(stage, gcursor, rowptr, cnt, csr, x, dt1,
                                  tgt, K1, cb1, pool1);
    // K_B: conv2 (512) || coop-gather1 (3125)
    k_B<<<512 + NGB, blk, 0, stream>>>(pool1, Wt2, cb2, pool2t,
                                       dt1, rowptr, cnt, csr, W1, b1, (float*)dt2);
    // K_C: conv3 N-split (1024) || coop-gather2 (3125)
    k_C<<<1024 + NGB, blk, 0, stream>>>(pool2t, Wt3, cb3, pool3,
                                        dt2, rowptr, cnt, csr, W2, b2, (unsigned*)dt3);
    // K_D: coop-gather3 (3125) || mean+Wxt (64)
    k_D<<<NGB + 64, blk, 0, stream>>>(dt3, rowptr, cnt, csr, W3, b3,
                                      batch, (unsigned*)g, pool3, Wxt, bxt, cx);

    // dense head (latency-hiding: >=512 blocks, 16-deep load batching)
    k_head_g<<<256, blk, 0, stream>>>(g, Wg1, bg1, gp1);
    k_gvec_ks<<<dim3(8, 64), blk, 0, stream>>>(gp1, Wg2, gvec);
    k_cat2<<<dim3(8, 64), blk, 0, stream>>>(gvec, cx, Wf1, xf1);
    k_xf2_ks<<<dim3(8, 64), blk, 0, stream>>>(xf1, Wf2, xf2);
    k_dense_out<<<4, blk, 0, stream>>>(xf2, Wo, bo, (float*)d_out);
}

// Round 12
// 394.577 us; speedup vs baseline: 1.1961x; 1.0175x over previous
//
#include <hip/hip_runtime.h>
#include <hip/hip_fp16.h>
#include <cstddef>

#define NA 200000
#define NE 3200000
#define NB 512
#define NBKT 256          // dst-range buckets
#define BKTN 782          // nodes per bucket
#define BKTCAP 16384      // stage capacity per bucket (exp 12500, sigma ~111)
#define NEPB 3200         // edges per pass-1 block (1000*3200 = NE)
#define NGB 3125          // gather blocks: 3125*64 = 200000 = NA exactly

// ---------------- fp16 helpers ----------------
typedef _Float16 hv2 __attribute__((ext_vector_type(2)));
typedef _Float16 half8 __attribute__((ext_vector_type(8)));
typedef float floatx4 __attribute__((ext_vector_type(4)));
union UH2 { unsigned u; __half2 h; hv2 v; };
__device__ __forceinline__ float4 h4f(unsigned a, unsigned b) {
    UH2 x, y; x.u = a; y.u = b;
    float2 fa = __half22float2(x.h), fb = __half22float2(y.h);
    return make_float4(fa.x, fa.y, fb.x, fb.y);
}
__device__ __forceinline__ unsigned f2h(float a, float b) {
    UH2 r; r.h = __float22half2_rn(make_float2(a, b));
    return r.u;
}

// -------- init: accumulator pre-init + weight repack to fp16 ---------------
__global__ void k_init(unsigned* g, int* gcursor,
                       float* gvec, const float* __restrict__ bg2,
                       float* xf2, const float* __restrict__ bf2,
                       float* xf1, const float* __restrict__ bf1,
                       const float* __restrict__ K2, const float* __restrict__ K3,
                       __half* __restrict__ Wt2, __half* __restrict__ Wt3) {
    int i = blockIdx.x * blockDim.x + threadIdx.x;
    if (i < NB * 16) g[i] = 0u;
    if (i < NBKT) gcursor[i] = i * BKTCAP;
    if (i < NB * 128) gvec[i] = bg2[i & 127];
    if (i < NB * 512) xf2[i] = bf2[i & 511];
    if (i < NB * 1024) xf1[i] = bf1[i & 1023];
    if (i < 64 * 32 * 8) {
        int o = i >> 8, rem = i & 255, c = rem >> 3, kk = rem & 7;
        Wt2[(o << 8) + (kk << 5) + c] = __float2half(K2[i]);
    }
    if (i < 128 * 64 * 8) {
        int o = i >> 9, rem = i & 511, c = rem >> 3, kk = rem & 7;
        Wt3[(o << 9) + (kk << 6) + c] = __float2half(K3[i]);
    }
}

// ------- conv1 device body (fp32 LDS/compute, fp16 output) -----------------
// PT=4: natural VGPR ~124. NO launch_bounds force (R7/R10: forcing below the
// live set spills). All 1024 conv1 blocks live in k_A, overlapped w/ binning.
template<int CIN, int COUT, int OBLK, int LIN, int PITCH, int POUT, int NTT>
__device__ __forceinline__ void dev_conv1(int b, int oy,
        const float* __restrict__ in, const float* __restrict__ Kw,
        const float* __restrict__ bias, __half* __restrict__ out,
        float* s_in) {
    constexpr int SPO = 256 / OBLK;
    constexpr int PT = (NTT < 4) ? NTT : 4;
    constexpr int NPASS = (NTT + PT - 1) / PT;
    for (int idx = threadIdx.x; idx < CIN * PITCH; idx += 256) s_in[idx] = 0.f;
    __syncthreads();
    for (int idx = threadIdx.x; idx < LIN * CIN; idx += 256) {
        int p = idx / CIN, c = idx - p * CIN;
        s_in[c * PITCH + p] = in[(size_t)b * (LIN * CIN) + idx];
    }
    __syncthreads();
    int ol = threadIdx.x / SPO;
    int s  = threadIdx.x - ol * SPO;
    int o  = oy * OBLK + ol;
    float bo = bias[o];
    const float* wrow = Kw + (size_t)o * CIN * 8;
    for (int pass = 0; pass < NPASS; pass++) {
        float acc[PT][12];
#pragma unroll
        for (int tt = 0; tt < PT; tt++)
#pragma unroll
            for (int j = 0; j < 12; j++) acc[tt][j] = 0.f;
        bool vld[PT]; int tgs[PT];
#pragma unroll
        for (int tt = 0; tt < PT; tt++) {
            int ta = pass * PT + tt;
            int tg = s + SPO * ta;
            tgs[tt] = tg;
            vld[tt] = (ta < NTT) && (4 * tg < POUT);
        }
        for (int i = 0; i < CIN; i++) {
            float wa[8];
            const float4* wp = (const float4*)(wrow + (size_t)i * 8);
            *(float4*)&wa[0] = wp[0];
            *(float4*)&wa[4] = wp[1];
#pragma unroll
            for (int tt = 0; tt < PT; tt++) {
                if (vld[tt]) {
                    const float4* xr = (const float4*)&s_in[i * PITCH + 12 * tgs[tt]];
                    float xa[20];
#pragma unroll
                    for (int q = 0; q < 5; q++) *(float4*)&xa[4 * q] = xr[q];
#pragma unroll
                    for (int j = 0; j < 12; j++) {
                        float sm = acc[tt][j];
#pragma unroll
                        for (int k = 0; k < 8; k++) sm = fmaf(xa[j + k], wa[k], sm);
                        acc[tt][j] = sm;
                    }
                }
            }
        }
#pragma unroll
        for (int tt = 0; tt < PT; tt++) {
            if (vld[tt]) {
#pragma unroll
                for (int p = 0; p < 4; p++) {
                    int P = 4 * tgs[tt] + p;
                    if (P < POUT) {
                        float m = fmaxf(fmaxf(acc[tt][3 * p], acc[tt][3 * p + 1]), acc[tt][3 * p + 2]);
                        out[((size_t)b * COUT + o) * POUT + P] = __float2half(fmaxf(m + bo, 0.f));
                    }
                }
            }
        }
    }
}

// ======================= MFMA conv2 ========================================
__device__ __forceinline__ void dev_conv2_mfma(int b,
        const __half* __restrict__ pool1, const __half* __restrict__ Wt2,
        const float* __restrict__ cb2, __half* __restrict__ pool2t,
        char* smem) {
    __half* sT   = (__half*)smem;   // [344][40] halves = 27520 B
    __half* outS = (__half*)smem;   // [336][68] halves = 45696 B (overlays sT)
    const __half* inp = pool1 + (size_t)b * (32 * 331);
    for (int idx = threadIdx.x; idx < 32 * 331; idx += 256) {
        int c = idx / 331;
        int p = idx - c * 331;
        sT[p * 40 + c] = inp[idx];              // LDS transpose (2B scattered)
    }
    __syncthreads();
    int lane = threadIdx.x & 63, wv = threadIdx.x >> 6;
    int l15 = lane & 15, lg = lane >> 4;
    int mtBeg = wv * 5;
    int nmt = (wv == 3) ? 6 : 5;
    const floatx4 FZ = {0.f, 0.f, 0.f, 0.f};
    floatx4 acc[6][4];
#pragma unroll
    for (int mi = 0; mi < 6; mi++)
#pragma unroll
        for (int nt = 0; nt < 4; nt++) acc[mi][nt] = FZ;
    const half8* WB = (const half8*)Wt2;
    for (int s = 0; s < 8; s++) {
        half8 bfr[4];
#pragma unroll
        for (int nt = 0; nt < 4; nt++)
            bfr[nt] = WB[(nt * 16 + l15) * 32 + s * 4 + lg];
        half8 afr[6];
#pragma unroll
        for (int mi = 0; mi < 6; mi++) {
            if (mi < nmt) {
                int row = (mtBeg + mi) * 16 + l15 + s;
                afr[mi] = *(const half8*)(sT + row * 40 + lg * 8);
            }
        }
#pragma unroll
        for (int mi = 0; mi < 6; mi++) {
            if (mi < nmt) {
#pragma unroll
                for (int nt = 0; nt < 4; nt++)
                    acc[mi][nt] = __builtin_amdgcn_mfma_f32_16x16x32_f16(
                        afr[mi], bfr[nt], acc[mi][nt], 0, 0, 0);
            }
        }
    }
    __syncthreads();                              // sT reads done; overlay outS
    float bo[4];
#pragma unroll
    for (int nt = 0; nt < 4; nt++) bo[nt] = cb2[nt * 16 + l15];
#pragma unroll
    for (int mi = 0; mi < 6; mi++) {
        if (mi < nmt) {
#pragma unroll
            for (int nt = 0; nt < 4; nt++) {
                int o = nt * 16 + l15;
#pragma unroll
                for (int r = 0; r < 4; r++) {
                    int p = (mtBeg + mi) * 16 + lg * 4 + r;
                    float v = fmaxf(acc[mi][nt][r] + bo[nt], 0.f);
                    outS[p * 68 + o] = __float2half(v);
                }
            }
        }
    }
    __syncthreads();
    __half* op = pool2t + (size_t)b * (108 * 64);
    for (int idx = threadIdx.x; idx < 108 * 64; idx += 256) {
        int P = idx >> 6, o = idx & 63;
        float v0 = __half2float(outS[(3 * P) * 68 + o]);
        float v1 = __half2float(outS[(3 * P + 1) * 68 + o]);
        float v2 = __half2float(outS[(3 * P + 2) * 68 + o]);
        op[idx] = __float2half(fmaxf(fmaxf(v0, v1), v2));   // [b][P][o]
    }
}

// ======================= MFMA conv3 (N-split halves) =======================
// acc[2][4] (32 VGPR): fused kernel's natural live set fits the <=64 bucket
// so launch_bounds(256,8) is SAFE here (verified: k_C Occ 50-65%, no spill).
__device__ __forceinline__ void dev_conv3_mfma(int b, int nh,
        const __half* __restrict__ pool2t, const __half* __restrict__ Wt3,
        const float* __restrict__ cb3, float* __restrict__ pool3,
        char* smem) {
    __half* sT  = (__half*)smem;   // [120][72] halves = 17280 B
    float* outS = (float*)smem;    // [48][68] fp32 = 13056 B (overlays sT)
    const uint4* inp = (const uint4*)(pool2t + (size_t)b * (108 * 64));
    for (int t = threadIdx.x; t < 108 * 8; t += 256) {
        int r = t >> 3, s8 = t & 7;
        *(uint4*)(sT + r * 72 + s8 * 8) = inp[t];
    }
    __syncthreads();
    int lane = threadIdx.x & 63, wv = threadIdx.x >> 6;
    int l15 = lane & 15, lg = lane >> 4;
    int mtBeg = wv * 2;
    int nmt = (wv == 3) ? 1 : 2;
    const floatx4 FZ = {0.f, 0.f, 0.f, 0.f};
    floatx4 acc[2][4];
#pragma unroll
    for (int mi = 0; mi < 2; mi++)
#pragma unroll
        for (int nt = 0; nt < 4; nt++) acc[mi][nt] = FZ;
    const half8* WB = (const half8*)Wt3;
    for (int s = 0; s < 16; s++) {
        half8 afr[2];
#pragma unroll
        for (int mi = 0; mi < 2; mi++) {
            if (mi < nmt) {
                int row = (mtBeg + mi) * 16 + l15 + (s >> 1);
                afr[mi] = *(const half8*)(sT + row * 72 + (s & 1) * 32 + lg * 8);
            }
        }
#pragma unroll
        for (int nt = 0; nt < 4; nt++) {
            half8 bfr = WB[((nh * 4 + nt) * 16 + l15) * 64 + s * 4 + lg];
            acc[0][nt] = __builtin_amdgcn_mfma_f32_16x16x32_f16(
                afr[0], bfr, acc[0][nt], 0, 0, 0);
            if (nmt > 1)
                acc[1][nt] = __builtin_amdgcn_mfma_f32_16x16x32_f16(
                    afr[1], bfr, acc[1][nt], 0, 0, 0);
        }
    }
    __syncthreads();                              // MFMA done; sT dead
    float bo[4];
#pragma unroll
    for (int nt = 0; nt < 4; nt++) bo[nt] = cb3[(nh * 4 + nt) * 16 + l15];
    float* op = pool3 + (size_t)b * (33 * 128);
    for (int pp = 0; pp < 3; pp++) {
        int t0 = 3 * pp;
#pragma unroll
        for (int mi = 0; mi < 2; mi++) {
            int tile = mtBeg + mi;
            if (mi < nmt && tile >= t0 && tile < t0 + 3) {
#pragma unroll
                for (int nt = 0; nt < 4; nt++) {
                    int ol = nt * 16 + l15;
#pragma unroll
                    for (int r = 0; r < 4; r++) {
                        int p = tile * 16 + lg * 4 + r;
                        if (p < 100)
                            outS[(p - 48 * pp) * 68 + ol] =
                                fmaxf(acc[mi][nt][r] + bo[nt], 0.f);
                    }
                }
            }
        }
        __syncthreads();
        int nP = (pp == 2) ? 1 : 16;
        for (int idx = threadIdx.x; idx < nP * 64; idx += 256) {
            int Pl = idx >> 6, ol = idx & 63;
            int P = 16 * pp + Pl;
            int p = 3 * P - 48 * pp;
            float v0 = outS[p * 68 + ol];
            float v1 = outS[(p + 1) * 68 + ol];
            float v2 = outS[(p + 2) * 68 + ol];
            op[P * 128 + (nh << 6) + ol] = fmaxf(fmaxf(v0, v1), v2);
        }
        __syncthreads();
    }
}

// -------- K_A: conv1 both halves (1024, FIRST) || pass1 binning (1000) -----
__global__ __launch_bounds__(256) void k_A(
        const int* __restrict__ src, const int* __restrict__ dst,
        int* __restrict__ gcursor, unsigned* __restrict__ stage,
        const float* __restrict__ tgt, const float* __restrict__ K1,
        const float* __restrict__ cb1, __half* __restrict__ pool1) {
    __shared__ __align__(16) char smem[20160];   // conv1 s_in OR sort arrays
    int bx = blockIdx.x;
    if (bx < 1024) {                              // LPT: long conv1 first
        dev_conv1<5, 32, 16, 1000, 1008, 331, 6>(bx >> 1, bx & 1, tgt, K1, cb1,
                                                 pool1, (float*)smem);
        return;
    }
    int* hcnt  = (int*)smem;                 // [256] count -> scan -> cursor
    int* hbase = hcnt + 256;                 // [256] global bucket base
    int* lbase = hbase + 256;                // [256] local bucket base
    unsigned* sbuf = (unsigned*)(lbase + 256);      // [3200] sorted entries
    unsigned char* sbkt = (unsigned char*)(sbuf + NEPB); // [3200] bucket ids
    int t = threadIdx.x;
    int e0 = (bx - 1024) * NEPB;
    hcnt[t] = 0;
    __syncthreads();
    const int4* d4 = (const int4*)(dst + e0);
    for (int i = t; i < NEPB / 4; i += 256) {
        int4 d = d4[i];
        atomicAdd(&hcnt[d.x / BKTN], 1);
        atomicAdd(&hcnt[d.y / BKTN], 1);
        atomicAdd(&hcnt[d.z / BKTN], 1);
        atomicAdd(&hcnt[d.w / BKTN], 1);
    }
    __syncthreads();
    int myc = hcnt[t];
    hbase[t] = atomicAdd(&gcursor[t], myc);
    __syncthreads();
    // in-place inclusive scan of hcnt (Hillis-Steele)
#pragma unroll
    for (int off = 1; off < 256; off <<= 1) {
        int u = (t >= off) ? hcnt[t - off] : 0;
        __syncthreads();
        hcnt[t] += u;
        __syncthreads();
    }
    lbase[t] = hcnt[t] - myc;   // exclusive base
    hcnt[t] = 0;                // reuse as per-bucket cursor
    __syncthreads();
    const int4* s4 = (const int4*)(src + e0);
    for (int i = t; i < NEPB / 4; i += 256) {
        int4 d = d4[i];
        int4 s = s4[i];
        int ds[4] = {d.x, d.y, d.z, d.w};
        int ss[4] = {s.x, s.y, s.z, s.w};
#pragma unroll
        for (int j = 0; j < 4; j++) {
            int bkt = ds[j] / BKTN;
            int dloc = ds[j] - bkt * BKTN;
            int k = atomicAdd(&hcnt[bkt], 1);
            int pos = lbase[bkt] + k;
            sbuf[pos] = ((unsigned)dloc << 18) | (unsigned)ss[j];
            sbkt[pos] = (unsigned char)bkt;
        }
    }
    __syncthreads();
    // coalesced copy-out: consecutive i -> consecutive stage addresses
    for (int i = t; i < NEPB; i += 256) {
        unsigned v = sbuf[i];
        int bkt = sbkt[i];
        stage[hbase[bkt] + (i - lbase[bkt])] = v;
    }
}

// -------- K_Bp: pure pass2 (256 blocks; low VGPR, high occupancy) ----------
__global__ __launch_bounds__(256) void k_Bp(
        const unsigned* __restrict__ stage, const int* __restrict__ gcursor,
        int* __restrict__ rowptr, int* __restrict__ cnt, int* __restrict__ csr,
        const float* __restrict__ x, float4* __restrict__ dt1) {
    __shared__ int lcnt[BKTN];
    __shared__ int lpos[BKTN];
    __shared__ int partial[256];
    __shared__ int sbase;
    int t = threadIdx.x;
    int bkt = blockIdx.x;
    int tot = gcursor[t] - t * BKTCAP;
    partial[t] = tot;
    __syncthreads();
#pragma unroll
    for (int off = 1; off < 256; off <<= 1) {
        int u = (t >= off) ? partial[t - off] : 0;
        __syncthreads();
        partial[t] += u;
        __syncthreads();
    }
    if (t == 0) sbase = (bkt == 0) ? 0 : partial[bkt - 1];
    __syncthreads();
    int base = sbase;
    int n0 = bkt * BKTN;
    int ncnt = (NA - n0 < BKTN) ? (NA - n0) : BKTN;
    int eBeg = bkt * BKTCAP;
    int eCnt = gcursor[bkt] - eBeg;
    for (int i = t; i < BKTN; i += 256) lcnt[i] = 0;
    __syncthreads();
    for (int i = t; i < eCnt; i += 256)
        atomicAdd(&lcnt[stage[eBeg + i] >> 18], 1);
    __syncthreads();
    int mysum = 0;
#pragma unroll
    for (int j = 0; j < 4; j++) {
        int node = 4 * t + j;
        if (node < ncnt) mysum += lcnt[node];
    }
    partial[t] = mysum;
    __syncthreads();
#pragma unroll
    for (int off = 1; off < 256; off <<= 1) {
        int u = (t >= off) ? partial[t - off] : 0;
        __syncthreads();
        partial[t] += u;
        __syncthreads();
    }
    int running = partial[t] - mysum;
#pragma unroll
    for (int j = 0; j < 4; j++) {
        int node = 4 * t + j;
        if (node < ncnt) {
            lpos[node] = running;
            rowptr[n0 + node] = base + running;
            cnt[n0 + node] = lcnt[node];
            running += lcnt[node];
        }
    }
    __syncthreads();
    for (int i = t; i < eCnt; i += 256) {
        unsigned v = stage[eBeg + i];
        int dloc = v >> 18;
        int s = v & 0x3FFFF;
        int k = atomicAdd(&lpos[dloc], 1);
        csr[base + k] = s;
    }
    for (int i = t; i < ncnt; i += 256) {
        int n = n0 + i;
        float4 p = ((const float4*)x)[n];
        float dv = rsqrtf((float)lcnt[i] + 1.0f);
        dt1[n] = make_float4(dv * p.x, dv * p.y, dv * p.z, dv * p.w);
    }
}

// -------- K_B: conv2 MFMA (512) || coop-gather1+W1 -> dt2 (3125) -----------
// 4 lanes/node: lane sub loads neighbors e=sub,sub+4,..., butterfly shfl_xor
// combines; lane sub computes output f=sub; 4B coalesced write.
__global__ __launch_bounds__(256) void k_B(
        const __half* __restrict__ pool1, const __half* __restrict__ Wt2,
        const float* __restrict__ cb2, __half* __restrict__ pool2t,
        const float4* __restrict__ dt1, const int* __restrict__ rowptr,
        const int* __restrict__ cnt, const int* __restrict__ csr,
        const float* __restrict__ W1, const float* __restrict__ b1,
        float* __restrict__ dt2f) {
    __shared__ __align__(16) char smem[45696];
    int bx = blockIdx.x;
    if (bx < 512) {
        dev_conv2_mfma(bx, pool1, Wt2, cb2, pool2t, smem);
        return;
    }
    __shared__ float sW[16];
    if (threadIdx.x < 16) sW[threadIdx.x] = W1[threadIdx.x];
    __syncthreads();
    int n   = (bx - 512) * 64 + (threadIdx.x >> 2);   // always < NA
    int sub = threadIdx.x & 3;
    int cn = cnt[n];
    float dv = rsqrtf((float)cn + 1.0f);
    const int* row = csr + rowptr[n];
    float4 selfv = dt1[n];                            // broadcast load
    float4 acc = make_float4(0.f, 0.f, 0.f, 0.f);
    if (sub == 0) acc = selfv;
    int e = sub;
    for (; e + 4 < cn; e += 8) {                      // 2 independent loads
        float4 v0 = dt1[row[e]];
        float4 v1 = dt1[row[e + 4]];
        acc.x += v0.x + v1.x; acc.y += v0.y + v1.y;
        acc.z += v0.z + v1.z; acc.w += v0.w + v1.w;
    }
    if (e < cn) {
        float4 v = dt1[row[e]];
        acc.x += v.x; acc.y += v.y; acc.z += v.z; acc.w += v.w;
    }
    // butterfly over the 4-lane group
    acc.x += __shfl_xor(acc.x, 1); acc.y += __shfl_xor(acc.y, 1);
    acc.z += __shfl_xor(acc.z, 1); acc.w += __shfl_xor(acc.w, 1);
    acc.x += __shfl_xor(acc.x, 2); acc.y += __shfl_xor(acc.y, 2);
    acc.z += __shfl_xor(acc.z, 2); acc.w += __shfl_xor(acc.w, 2);
    float a[4] = {acc.x, acc.y, acc.z, acc.w};
    float s = 0.f;
#pragma unroll
    for (int k = 0; k < 4; k++) s = fmaf(a[k], sW[k * 4 + sub], s);
    float o = dv * fmaxf(fmaf(dv, s, b1[sub]), 0.f);  // dt2 = dv*relu(...)
    dt2f[(size_t)n * 4 + sub] = o;
}

// -------- K_C: conv3 N-split (1024) || coop-gather2+W2 -> dt3 (3125) -------
// launch_bounds(256,8): fused live set ~32 regs, no spill risk (verified).
__global__ __launch_bounds__(256, 8) void k_C(
        const __half* __restrict__ pool2t, const __half* __restrict__ Wt3,
        const float* __restrict__ cb3, float* __restrict__ pool3,
        const float4* __restrict__ dt2, const int* __restrict__ rowptr,
        const int* __restrict__ cnt, const int* __restrict__ csr,
        const float* __restrict__ W2, const float* __restrict__ b2,
        unsigned* __restrict__ dt3u) {
    __shared__ __align__(16) char smem[17280];
    int bx = blockIdx.x;
    if (bx < 1024) {
        dev_conv3_mfma(bx & 511, bx >> 9, pool2t, Wt3, cb3, pool3, smem);
        return;
    }
    __shared__ float sW[32];
    if (threadIdx.x < 32) sW[threadIdx.x] = W2[threadIdx.x];
    __syncthreads();
    int n   = (bx - 1024) * 64 + (threadIdx.x >> 2);
    int sub = threadIdx.x & 3;
    int cn = cnt[n];
    float dv = rsqrtf((float)cn + 1.0f);
    const int* row = csr + rowptr[n];
    float4 selfv = dt2[n];
    float4 acc = make_float4(0.f, 0.f, 0.f, 0.f);
    if (sub == 0) acc = selfv;
    int e = sub;
    for (; e + 4 < cn; e += 8) {
        float4 v0 = dt2[row[e]];
        float4 v1 = dt2[row[e + 4]];
        acc.x += v0.x + v1.x; acc.y += v0.y + v1.y;
        acc.z += v0.z + v1.z; acc.w += v0.w + v1.w;
    }
    if (e < cn) {
        float4 v = dt2[row[e]];
        acc.x += v.x; acc.y += v.y; acc.z += v.z; acc.w += v.w;
    }
    acc.x += __shfl_xor(acc.x, 1); acc.y += __shfl_xor(acc.y, 1);
    acc.z += __shfl_xor(acc.z, 1); acc.w += __shfl_xor(acc.w, 1);
    acc.x += __shfl_xor(acc.x, 2); acc.y += __shfl_xor(acc.y, 2);
    acc.z += __shfl_xor(acc.z, 2); acc.w += __shfl_xor(acc.w, 2);
    float a[4] = {acc.x, acc.y, acc.z, acc.w};
    int f0 = 2 * sub;
    float s0 = 0.f, s1 = 0.f;
#pragma unroll
    for (int k = 0; k < 4; k++) {
        s0 = fmaf(a[k], sW[k * 8 + f0], s0);
        s1 = fmaf(a[k], sW[k * 8 + f0 + 1], s1);
    }
    float o0 = dv * fmaxf(fmaf(dv, s0, b2[f0]), 0.f);
    float o1 = dv * fmaxf(fmaf(dv, s1, b2[f0 + 1]), 0.f);
    dt3u[(size_t)n * 4 + sub] = f2h(o0, o1);
}

// -------- K_D: coop-gather3(fp16)+W3+segmax (3125) || mean+Wxt (64) --------
__global__ __launch_bounds__(256) void k_D(
        const uint4* __restrict__ dt3, const int* __restrict__ rowptr,
        const int* __restrict__ cnt, const int* __restrict__ csr,
        const float* __restrict__ W3, const float* __restrict__ b3,
        const int* __restrict__ batch, unsigned* __restrict__ g,
        const float* __restrict__ pool3, const float* __restrict__ Wxt,
        const float* __restrict__ bxt, float* __restrict__ cx) {
    int bx = blockIdx.x;
    if (bx >= NGB) {
        __shared__ float sa[8 * 128];
        int b0 = (bx - NGB) * 8;
        for (int t = threadIdx.x; t < 8 * 128; t += 256) {
            int gg = t >> 7, k = t & 127;
            // pool3 layout [b][P=33][o=128]; lanes read consecutive o
            const float* r = pool3 + (size_t)(b0 + gg) * (33 * 128) + k;
            float s = 0.f;
#pragma unroll
            for (int p = 0; p < 33; p++) s += r[p * 128];
            sa[t] = s * (1.f / 33.f);
        }
        __syncthreads();
        int j = threadIdx.x;
        if (j >= 128) return;
        float bj = bxt[j];
        float acc[8];
#pragma unroll
        for (int gg = 0; gg < 8; gg++) acc[gg] = bj;
#pragma unroll 4
        for (int k = 0; k < 128; k++) {
            float w = Wxt[(size_t)k * 128 + j];
#pragma unroll
            for (int gg = 0; gg < 8; gg++) acc[gg] = fmaf(sa[gg * 128 + k], w, acc[gg]);
        }
#pragma unroll
        for (int gg = 0; gg < 8; gg++)
            cx[(size_t)(b0 + gg) * 128 + j] = fmaxf(acc[gg], 0.f);
        return;
    }
    __shared__ float sW[128];
    __shared__ unsigned sg[32];
    __shared__ int sbmin;
    if (threadIdx.x < 128) sW[threadIdx.x] = W3[threadIdx.x];
    if (threadIdx.x < 32) sg[threadIdx.x] = 0u;
    if (threadIdx.x == 0) sbmin = batch[bx * 64];
    __syncthreads();
    int n   = bx * 64 + (threadIdx.x >> 2);          // always < NA
    int sub = threadIdx.x & 3;
    int cn = cnt[n];
    float dv = rsqrtf((float)cn + 1.0f);
    const int* row = csr + rowptr[n];
    uint4 sv = dt3[n];
    float4 slo = h4f(sv.x, sv.y), shi = h4f(sv.z, sv.w);
    float a0 = 0.f, a1 = 0.f, a2 = 0.f, a3 = 0.f;
    float a4 = 0.f, a5 = 0.f, a6 = 0.f, a7 = 0.f;
    if (sub == 0) {
        a0 = slo.x; a1 = slo.y; a2 = slo.z; a3 = slo.w;
        a4 = shi.x; a5 = shi.y; a6 = shi.z; a7 = shi.w;
    }
    int e = sub;
    for (; e + 4 < cn; e += 8) {
        uint4 p0 = dt3[row[e]], p1 = dt3[row[e + 4]];
        float4 l0 = h4f(p0.x, p0.y), h0 = h4f(p0.z, p0.w);
        float4 l1 = h4f(p1.x, p1.y), h1 = h4f(p1.z, p1.w);
        a0 += l0.x + l1.x; a1 += l0.y + l1.y;
        a2 += l0.z + l1.z; a3 += l0.w + l1.w;
        a4 += h0.x + h1.x; a5 += h0.y + h1.y;
        a6 += h0.z + h1.z; a7 += h0.w + h1.w;
    }
    if (e < cn) {
        uint4 p = dt3[row[e]];
        float4 l = h4f(p.x, p.y), h = h4f(p.z, p.w);
        a0 += l.x; a1 += l.y; a2 += l.z; a3 += l.w;
        a4 += h.x; a5 += h.y; a6 += h.z; a7 += h.w;
    }
    a0 += __shfl_xor(a0, 1); a1 += __shfl_xor(a1, 1);
    a2 += __shfl_xor(a2, 1); a3 += __shfl_xor(a3, 1);
    a4 += __shfl_xor(a4, 1); a5 += __shfl_xor(a5, 1);
    a6 += __shfl_xor(a6, 1); a7 += __shfl_xor(a7, 1);
    a0 += __shfl_xor(a0, 2); a1 += __shfl_xor(a1, 2);
    a2 += __shfl_xor(a2, 2); a3 += __shfl_xor(a3, 2);
    a4 += __shfl_xor(a4, 2); a5 += __shfl_xor(a5, 2);
    a6 += __shfl_xor(a6, 2); a7 += __shfl_xor(a7, 2);
    float af[8] = {a0, a1, a2, a3, a4, a5, a6, a7};
    int rb = batch[n] - sbmin;
    if (rb > 1) rb = 1;
#pragma unroll
    for (int j = 0; j < 4; j++) {
        int f = sub * 4 + j;
        float s = 0.f;
#pragma unroll
        for (int k = 0; k < 8; k++) s = fmaf(af[k], sW[k * 16 + f], s);
        float r = fmaxf(fmaf(dv, s, b3[f]), 0.f);
        atomicMax(&sg[rb * 16 + f], __float_as_uint(r));
    }
    __syncthreads();
    if (threadIdx.x < 32) {
        unsigned v = sg[threadIdx.x];
        int rb2 = threadIdx.x >> 4, f = threadIdx.x & 15;
        int bbn = sbmin + rb2;
        if (v != 0u && bbn < NB) atomicMax(&g[bbn * 16 + f], v);
    }
}

// -------- head: g@Wg1 -> gp1 (relu), 256 blocks ----------------------------
__global__ __launch_bounds__(256) void k_head_g(
        const float* __restrict__ g, const float* __restrict__ Wg1,
        const float* __restrict__ bg1, float* __restrict__ gp1) {
    __shared__ float sa[8 * 16];
    int bx = blockIdx.x;
    int b0 = (bx >> 2) * 8;
    if (threadIdx.x < 128)
        sa[threadIdx.x] = g[b0 * 16 + threadIdx.x];
    __syncthreads();
    int j = (bx & 3) * 256 + threadIdx.x;
    float bj = bg1[j];
    float acc[8];
#pragma unroll
    for (int gg = 0; gg < 8; gg++) acc[gg] = bj;
#pragma unroll
    for (int k = 0; k < 16; k++) {
        float w = Wg1[(size_t)k * 1024 + j];
#pragma unroll
        for (int gg = 0; gg < 8; gg++) acc[gg] = fmaf(sa[gg * 16 + k], w, acc[gg]);
    }
#pragma unroll
    for (int gg = 0; gg < 8; gg++)
        gp1[(size_t)(b0 + gg) * 1024 + j] = fmaxf(acc[gg], 0.f);
}

// -------- gvec += (gp1 K-slice)@Wg2 ; grid (8,64), 16-deep batching --------
__global__ __launch_bounds__(256) void k_gvec_ks(
        const float* __restrict__ gp1, const float* __restrict__ Wg2,
        float* __restrict__ gvec) {
    __shared__ float sa[8 * 128];
    int k0 = blockIdx.x * 128;
    int b0 = blockIdx.y * 8;
    for (int t = threadIdx.x; t < 8 * 128; t += 256) {
        int gg = t >> 7, k = t & 127;
        sa[t] = gp1[(size_t)(b0 + gg) * 1024 + k0 + k];
    }
    __syncthreads();
    int j  = threadIdx.x & 127;
    int kh = (threadIdx.x >> 7) * 64;            // 0 or 64
    const float* Wp = Wg2 + (size_t)(k0 + kh) * 128 + j;
    float acc[8];
#pragma unroll
    for (int gg = 0; gg < 8; gg++) acc[gg] = 0.f;
    for (int k = 0; k < 64; k += 16) {
        float w[16];
#pragma unroll
        for (int u = 0; u < 16; u++) w[u] = Wp[(size_t)(k + u) * 128];
#pragma unroll
        for (int u = 0; u < 16; u++) {
#pragma unroll
            for (int gg = 0; gg < 8; gg++)
                acc[gg] = fmaf(sa[gg * 128 + kh + k + u], w[u], acc[gg]);
        }
    }
#pragma unroll
    for (int gg = 0; gg < 8; gg++)
        atomicAdd(&gvec[(size_t)(b0 + gg) * 128 + j], acc[gg]);
}

// -------- xf1 += ([gvec|cx] K-half)@Wf1 ; grid (8,64): 4j x 2kh ------------
__global__ __launch_bounds__(256) void k_cat2(
        const float* __restrict__ gvec, const float* __restrict__ cx,
        const float* __restrict__ Wf1, float* __restrict__ xf1) {
    __shared__ float sa[8 * 128];
    int jx = blockIdx.x & 3;
    int kh = blockIdx.x >> 2;                    // 0: gvec rows, 1: cx rows
    int b0 = blockIdx.y * 8;
    const float* A = kh ? cx : gvec;
    for (int t = threadIdx.x; t < 8 * 128; t += 256) {
        int gg = t >> 7, k = t & 127;
        sa[t] = A[(size_t)(b0 + gg) * 128 + k];
    }
    __syncthreads();
    int j = jx * 256 + threadIdx.x;
    const float* Wp = Wf1 + (size_t)(kh * 128) * 1024 + j;
    float acc[8];
#pragma unroll
    for (int gg = 0; gg < 8; gg++) acc[gg] = 0.f;
    for (int k = 0; k < 128; k += 16) {
        float w[16];
#pragma unroll
        for (int u = 0; u < 16; u++) w[u] = Wp[(size_t)(k + u) * 1024];
#pragma unroll
        for (int u = 0; u < 16; u++) {
#pragma unroll
            for (int gg = 0; gg < 8; gg++)
                acc[gg] = fmaf(sa[gg * 128 + k + u], w[u], acc[gg]);
        }
    }
#pragma unroll
    for (int gg = 0; gg < 8; gg++)
        atomicAdd(&xf1[(size_t)(b0 + gg) * 1024 + j], acc[gg]);
}

// -------- xf2 += relu(xf1 K-slice)@Wf2 ; grid (8,64): 2j x 4kc -------------
__global__ __launch_bounds__(256) void k_xf2_ks(
        const float* __restrict__ xf1, const float* __restrict__ Wf2,
        float* __restrict__ xf2) {
    __shared__ float sa[8 * 256];
    int jb = blockIdx.x & 1;
    int k0 = (blockIdx.x >> 1) * 256;
    int b0 = blockIdx.y * 8;
    for (int t = threadIdx.x; t < 8 * 256; t += 256) {
        int gg = t >> 8, k = t & 255;
        sa[t] = fmaxf(xf1[(size_t)(b0 + gg) * 1024 + k0 + k], 0.f);  // deferred relu
    }
    __syncthreads();
    int j = jb * 256 + threadIdx.x;
    const float* Wp = Wf2 + (size_t)k0 * 512 + j;
    float acc[8];
#pragma unroll
    for (int gg = 0; gg < 8; gg++) acc[gg] = 0.f;
    for (int k = 0; k < 256; k += 16) {
        float w[16];
#pragma unroll
        for (int u = 0; u < 16; u++) w[u] = Wp[(size_t)(k + u) * 512];
#pragma unroll
        for (int u = 0; u < 16; u++) {
#pragma unroll
            for (int gg = 0; gg < 8; gg++)
                acc[gg] = fmaf(sa[gg * 256 + k + u], w[u], acc[gg]);
        }
    }
#pragma unroll
    for (int gg = 0; gg < 8; gg++)
        atomicAdd(&xf2[(size_t)(b0 + gg) * 512 + j], acc[gg]);
}

// final 512->2 layer; applies the deferred relu on xf2; float4 A-loads
__global__ __launch_bounds__(256) void k_dense_out(
        const float* __restrict__ A, const float* __restrict__ W,
        const float* __restrict__ bias, float* __restrict__ out) {
    int idx = blockIdx.x * 256 + threadIdx.x;
    if (idx >= NB * 2) return;
    int b = idx >> 1, j = idx & 1;
    float s = bias[j];
    const float4* A4 = (const float4*)(A + (size_t)b * 512);
    for (int k4 = 0; k4 < 128; k4 += 8) {
        float4 av[8];
#pragma unroll
        for (int u = 0; u < 8; u++) av[u] = A4[k4 + u];
#pragma unroll
        for (int u = 0; u < 8; u++) {
            int kb = (k4 + u) * 4;
            s = fmaf(fmaxf(av[u].x, 0.f), W[(kb + 0) * 2 + j], s);
            s = fmaf(fmaxf(av[u].y, 0.f), W[(kb + 1) * 2 + j], s);
            s = fmaf(fmaxf(av[u].z, 0.f), W[(kb + 2) * 2 + j], s);
            s = fmaf(fmaxf(av[u].w, 0.f), W[(kb + 3) * 2 + j], s);
        }
    }
    out[idx] = s;
}

extern "C" void kernel_launch(void* const* d_in, const int* in_sizes, int n_in,
                              void* d_out, int out_size, void* d_ws, size_t ws_size,
                              hipStream_t stream) {
    (void)in_sizes; (void)n_in; (void)out_size; (void)ws_size;
    const float* x   = (const float*)d_in[0];
    const int*  ei   = (const int*)d_in[1];
    const int*  batch= (const int*)d_in[2];
    const float* tgt = (const float*)d_in[3];
    const float* W1  = (const float*)d_in[4];  const float* b1  = (const float*)d_in[5];
    const float* W2  = (const float*)d_in[6];  const float* b2  = (const float*)d_in[7];
    const float* W3  = (const float*)d_in[8];  const float* b3  = (const float*)d_in[9];
    const float* Wg1 = (const float*)d_in[10]; const float* bg1 = (const float*)d_in[11];
    const float* Wg2 = (const float*)d_in[12]; const float* bg2 = (const float*)d_in[13];
    const float* K1  = (const float*)d_in[14]; const float* cb1 = (const float*)d_in[15];
    const float* K2  = (const float*)d_in[16]; const float* cb2 = (const float*)d_in[17];
    const float* K3  = (const float*)d_in[18]; const float* cb3 = (const float*)d_in[19];
    const float* Wxt = (const float*)d_in[20]; const float* bxt = (const float*)d_in[21];
    const float* Wf1 = (const float*)d_in[22]; const float* bf1 = (const float*)d_in[23];
    const float* Wf2 = (const float*)d_in[24]; const float* bf2 = (const float*)d_in[25];
    const float* Wo  = (const float*)d_in[26]; const float* bo  = (const float*)d_in[27];
    const int* srcp = ei;        // edge_index[0]
    const int* dstp = ei + NE;   // edge_index[1]

    float* ws = (float*)d_ws;
    float4* dt1 = (float4*)ws; ws += (size_t)NA * 4;   // dis*x          (3.2 MB)
    float4* dt2 = (float4*)ws; ws += (size_t)NA * 4;   // dis*out1       (3.2 MB)
    uint4*  dt3 = (uint4*)ws;  ws += (size_t)NA * 4;   // dis*out2 fp16  (3.2 MB)
    float* g     = ws; ws += NB * 16;
    float* gp1   = ws; ws += NB * 1024;
    float* gvec  = ws; ws += NB * 128;
    float* cx    = ws; ws += NB * 128;
    float* xf1   = ws; ws += NB * 1024;
    float* xf2   = ws; ws += NB * 512;
    __half* pool1 = (__half*)ws; ws += (size_t)NB * 32 * 331;   // fp16 (half used)
    __half* pool2t = (__half*)ws; ws += (size_t)NB * 64 * 108;  // fp16 [b][P][64]
    float* pool3 = ws; ws += (size_t)NB * 128 * 33;             // fp32 [b][33][128]
    __half* Wt2 = (__half*)ws; ws += 64 * 256 / 2;              // fp16 tap-major
    __half* Wt3 = (__half*)ws; ws += 128 * 512 / 2;             // fp16 tap-major
    int*   cnt    = (int*)ws; ws += NA;
    int*   rowptr = (int*)ws; ws += NA;
    int*   csr    = (int*)ws; ws += NE;               // compact CSR
    int*   gcursor= (int*)ws; ws += NBKT;
    unsigned* stage = (unsigned*)ws; ws += (size_t)NBKT * BKTCAP; // 16.8 MB

    dim3 blk(256);

    k_init<<<2048, blk, 0, stream>>>((unsigned*)g, gcursor, gvec, bg2, xf2, bf2,
                                     xf1, bf1, K2, K3, Wt2, Wt3);
    // K_A: conv1 both halves (1024 first, LPT) || pass1 binning (1000)
    k_A<<<2024, blk, 0, stream>>>(srcp, dstp, gcursor, stage, tgt, K1, cb1, pool1);
    // K_Bp: pure pass2 (256)
    k_Bp<<<256, blk, 0, stream>>>(stage, gcursor, rowptr, cnt, csr, x, dt1);
    // K_B: conv2 (512) || coop-gather1 (3125)
    k_B<<<512 + NGB, blk, 0, stream>>>(pool1, Wt2, cb2, pool2t,
                                       dt1, rowptr, cnt, csr, W1, b1, (float*)dt2);
    // K_C: conv3 N-split (1024) || coop-gather2 (3125)
    k_C<<<1024 + NGB, blk, 0, stream>>>(pool2t, Wt3, cb3, pool3,
                                        dt2, rowptr, cnt, csr, W2, b2, (unsigned*)dt3);
    // K_D: coop-gather3 (3125) || mean+Wxt (64)
    k_D<<<NGB + 64, blk, 0, stream>>>(dt3, rowptr, cnt, csr, W3, b3,
                                      batch, (unsigned*)g, pool3, Wxt, bxt, cx);

    // dense head (latency-hiding: >=512 blocks, 16-deep load batching)
    k_head_g<<<256, blk, 0, stream>>>(g, Wg1, bg1, gp1);
    k_gvec_ks<<<dim3(8, 64), blk, 0, stream>>>(gp1, Wg2, gvec);
    k_cat2<<<dim3(8, 64), blk, 0, stream>>>(gvec, cx, Wf1, xf1);
    k_xf2_ks<<<dim3(8, 64), blk, 0, stream>>>(xf1, Wf2, xf2);
    k_dense_out<<<4, blk, 0, stream>>>(xf2, Wo, bo, (float*)d_out);
}

// Round 13
// 393.270 us; speedup vs baseline: 1.2001x; 1.0033x over previous
//
#include <hip/hip_runtime.h>
#include <hip/hip_fp16.h>
#include <cstddef>

#define NA 200000
#define NE 3200000
#define NB 512
#define NBKT 256          // dst-range buckets
#define BKTN 782          // nodes per bucket
#define BKTCAP 16384      // stage capacity per bucket (exp 12500, sigma ~111)
#define NEPB 3200         // edges per pass-1 block (1000*3200 = NE)
#define NGB 3125          // gather blocks: 3125*64 = 200000 = NA exactly

// ---------------- fp16 helpers ----------------
typedef _Float16 hv2 __attribute__((ext_vector_type(2)));
typedef _Float16 half8 __attribute__((ext_vector_type(8)));
typedef float floatx4 __attribute__((ext_vector_type(4)));
union UH2 { unsigned u; __half2 h; hv2 v; };
__device__ __forceinline__ float4 h4f(unsigned a, unsigned b) {
    UH2 x, y; x.u = a; y.u = b;
    float2 fa = __half22float2(x.h), fb = __half22float2(y.h);
    return make_float4(fa.x, fa.y, fb.x, fb.y);
}
__device__ __forceinline__ unsigned f2h(float a, float b) {
    UH2 r; r.h = __float22half2_rn(make_float2(a, b));
    return r.u;
}

// -------- init: accumulator pre-init + weight repack to fp16 ---------------
__global__ void k_init(unsigned* g, int* gcursor,
                       float* gvec, const float* __restrict__ bg2,
                       float* xf2, const float* __restrict__ bf2,
                       float* xf1, const float* __restrict__ bf1,
                       const float* __restrict__ K2, const float* __restrict__ K3,
                       __half* __restrict__ Wt2, __half* __restrict__ Wt3) {
    int i = blockIdx.x * blockDim.x + threadIdx.x;
    if (i < NB * 16) g[i] = 0u;
    if (i < NBKT) gcursor[i] = i * BKTCAP;
    if (i < NB * 128) gvec[i] = bg2[i & 127];
    if (i < NB * 512) xf2[i] = bf2[i & 511];
    if (i < NB * 1024) xf1[i] = bf1[i & 1023];
    if (i < 64 * 32 * 8) {
        int o = i >> 8, rem = i & 255, c = rem >> 3, kk = rem & 7;
        Wt2[(o << 8) + (kk << 5) + c] = __float2half(K2[i]);
    }
    if (i < 128 * 64 * 8) {
        int o = i >> 9, rem = i & 511, c = rem >> 3, kk = rem & 7;
        Wt3[(o << 9) + (kk << 6) + c] = __float2half(K3[i]);
    }
}

// ------- conv1 device body (fp32 LDS/compute, fp16 output) -----------------
// PT=4: merged-kernel natural VGPR ~56 (R12 measured). NO launch_bounds
// force (R7/R10: forcing below the live set spills).
template<int CIN, int COUT, int OBLK, int LIN, int PITCH, int POUT, int NTT>
__device__ __forceinline__ void dev_conv1(int b, int oy,
        const float* __restrict__ in, const float* __restrict__ Kw,
        const float* __restrict__ bias, __half* __restrict__ out,
        float* s_in) {
    constexpr int SPO = 256 / OBLK;
    constexpr int PT = (NTT < 4) ? NTT : 4;
    constexpr int NPASS = (NTT + PT - 1) / PT;
    for (int idx = threadIdx.x; idx < CIN * PITCH; idx += 256) s_in[idx] = 0.f;
    __syncthreads();
    for (int idx = threadIdx.x; idx < LIN * CIN; idx += 256) {
        int p = idx / CIN, c = idx - p * CIN;
        s_in[c * PITCH + p] = in[(size_t)b * (LIN * CIN) + idx];
    }
    __syncthreads();
    int ol = threadIdx.x / SPO;
    int s  = threadIdx.x - ol * SPO;
    int o  = oy * OBLK + ol;
    float bo = bias[o];
    const float* wrow = Kw + (size_t)o * CIN * 8;
    for (int pass = 0; pass < NPASS; pass++) {
        float acc[PT][12];
#pragma unroll
        for (int tt = 0; tt < PT; tt++)
#pragma unroll
            for (int j = 0; j < 12; j++) acc[tt][j] = 0.f;
        bool vld[PT]; int tgs[PT];
#pragma unroll
        for (int tt = 0; tt < PT; tt++) {
            int ta = pass * PT + tt;
            int tg = s + SPO * ta;
            tgs[tt] = tg;
            vld[tt] = (ta < NTT) && (4 * tg < POUT);
        }
        for (int i = 0; i < CIN; i++) {
            float wa[8];
            const float4* wp = (const float4*)(wrow + (size_t)i * 8);
            *(float4*)&wa[0] = wp[0];
            *(float4*)&wa[4] = wp[1];
#pragma unroll
            for (int tt = 0; tt < PT; tt++) {
                if (vld[tt]) {
                    const float4* xr = (const float4*)&s_in[i * PITCH + 12 * tgs[tt]];
                    float xa[20];
#pragma unroll
                    for (int q = 0; q < 5; q++) *(float4*)&xa[4 * q] = xr[q];
#pragma unroll
                    for (int j = 0; j < 12; j++) {
                        float sm = acc[tt][j];
#pragma unroll
                        for (int k = 0; k < 8; k++) sm = fmaf(xa[j + k], wa[k], sm);
                        acc[tt][j] = sm;
                    }
                }
            }
        }
#pragma unroll
        for (int tt = 0; tt < PT; tt++) {
            if (vld[tt]) {
#pragma unroll
                for (int p = 0; p < 4; p++) {
                    int P = 4 * tgs[tt] + p;
                    if (P < POUT) {
                        float m = fmaxf(fmaxf(acc[tt][3 * p], acc[tt][3 * p + 1]), acc[tt][3 * p + 2]);
                        out[((size_t)b * COUT + o) * POUT + P] = __float2half(fmaxf(m + bo, 0.f));
                    }
                }
            }
        }
    }
}

// ======================= MFMA conv2 ========================================
__device__ __forceinline__ void dev_conv2_mfma(int b,
        const __half* __restrict__ pool1, const __half* __restrict__ Wt2,
        const float* __restrict__ cb2, __half* __restrict__ pool2t,
        char* smem) {
    __half* sT   = (__half*)smem;   // [344][40] halves = 27520 B
    __half* outS = (__half*)smem;   // [336][68] halves = 45696 B (overlays sT)
    const __half* inp = pool1 + (size_t)b * (32 * 331);
    for (int idx = threadIdx.x; idx < 32 * 331; idx += 256) {
        int c = idx / 331;
        int p = idx - c * 331;
        sT[p * 40 + c] = inp[idx];              // LDS transpose (2B scattered)
    }
    __syncthreads();
    int lane = threadIdx.x & 63, wv = threadIdx.x >> 6;
    int l15 = lane & 15, lg = lane >> 4;
    int mtBeg = wv * 5;
    int nmt = (wv == 3) ? 6 : 5;
    const floatx4 FZ = {0.f, 0.f, 0.f, 0.f};
    floatx4 acc[6][4];
#pragma unroll
    for (int mi = 0; mi < 6; mi++)
#pragma unroll
        for (int nt = 0; nt < 4; nt++) acc[mi][nt] = FZ;
    const half8* WB = (const half8*)Wt2;
    for (int s = 0; s < 8; s++) {
        half8 bfr[4];
#pragma unroll
        for (int nt = 0; nt < 4; nt++)
            bfr[nt] = WB[(nt * 16 + l15) * 32 + s * 4 + lg];
        half8 afr[6];
#pragma unroll
        for (int mi = 0; mi < 6; mi++) {
            if (mi < nmt) {
                int row = (mtBeg + mi) * 16 + l15 + s;
                afr[mi] = *(const half8*)(sT + row * 40 + lg * 8);
            }
        }
#pragma unroll
        for (int mi = 0; mi < 6; mi++) {
            if (mi < nmt) {
#pragma unroll
                for (int nt = 0; nt < 4; nt++)
                    acc[mi][nt] = __builtin_amdgcn_mfma_f32_16x16x32_f16(
                        afr[mi], bfr[nt], acc[mi][nt], 0, 0, 0);
            }
        }
    }
    __syncthreads();                              // sT reads done; overlay outS
    float bo[4];
#pragma unroll
    for (int nt = 0; nt < 4; nt++) bo[nt] = cb2[nt * 16 + l15];
#pragma unroll
    for (int mi = 0; mi < 6; mi++) {
        if (mi < nmt) {
#pragma unroll
            for (int nt = 0; nt < 4; nt++) {
                int o = nt * 16 + l15;
#pragma unroll
                for (int r = 0; r < 4; r++) {
                    int p = (mtBeg + mi) * 16 + lg * 4 + r;
                    float v = fmaxf(acc[mi][nt][r] + bo[nt], 0.f);
                    outS[p * 68 + o] = __float2half(v);
                }
            }
        }
    }
    __syncthreads();
    __half* op = pool2t + (size_t)b * (108 * 64);
    for (int idx = threadIdx.x; idx < 108 * 64; idx += 256) {
        int P = idx >> 6, o = idx & 63;
        float v0 = __half2float(outS[(3 * P) * 68 + o]);
        float v1 = __half2float(outS[(3 * P + 1) * 68 + o]);
        float v2 = __half2float(outS[(3 * P + 2) * 68 + o]);
        op[idx] = __float2half(fmaxf(fmaxf(v0, v1), v2));   // [b][P][o]
    }
}

// ======================= MFMA conv3 (N-split halves) =======================
// acc[2][4] (32 VGPR): fused kernel's natural live set fits the <=64 bucket
// so launch_bounds(256,8) is SAFE here (verified: k_C Occ 50-65%, no spill).
__device__ __forceinline__ void dev_conv3_mfma(int b, int nh,
        const __half* __restrict__ pool2t, const __half* __restrict__ Wt3,
        const float* __restrict__ cb3, float* __restrict__ pool3,
        char* smem) {
    __half* sT  = (__half*)smem;   // [120][72] halves = 17280 B
    float* outS = (float*)smem;    // [48][68] fp32 = 13056 B (overlays sT)
    const uint4* inp = (const uint4*)(pool2t + (size_t)b * (108 * 64));
    for (int t = threadIdx.x; t < 108 * 8; t += 256) {
        int r = t >> 3, s8 = t & 7;
        *(uint4*)(sT + r * 72 + s8 * 8) = inp[t];
    }
    __syncthreads();
    int lane = threadIdx.x & 63, wv = threadIdx.x >> 6;
    int l15 = lane & 15, lg = lane >> 4;
    int mtBeg = wv * 2;
    int nmt = (wv == 3) ? 1 : 2;
    const floatx4 FZ = {0.f, 0.f, 0.f, 0.f};
    floatx4 acc[2][4];
#pragma unroll
    for (int mi = 0; mi < 2; mi++)
#pragma unroll
        for (int nt = 0; nt < 4; nt++) acc[mi][nt] = FZ;
    const half8* WB = (const half8*)Wt3;
    for (int s = 0; s < 16; s++) {
        half8 afr[2];
#pragma unroll
        for (int mi = 0; mi < 2; mi++) {
            if (mi < nmt) {
                int row = (mtBeg + mi) * 16 + l15 + (s >> 1);
                afr[mi] = *(const half8*)(sT + row * 72 + (s & 1) * 32 + lg * 8);
            }
        }
#pragma unroll
        for (int nt = 0; nt < 4; nt++) {
            half8 bfr = WB[((nh * 4 + nt) * 16 + l15) * 64 + s * 4 + lg];
            acc[0][nt] = __builtin_amdgcn_mfma_f32_16x16x32_f16(
                afr[0], bfr, acc[0][nt], 0, 0, 0);
            if (nmt > 1)
                acc[1][nt] = __builtin_amdgcn_mfma_f32_16x16x32_f16(
                    afr[1], bfr, acc[1][nt], 0, 0, 0);
        }
    }
    __syncthreads();                              // MFMA done; sT dead
    float bo[4];
#pragma unroll
    for (int nt = 0; nt < 4; nt++) bo[nt] = cb3[(nh * 4 + nt) * 16 + l15];
    float* op = pool3 + (size_t)b * (33 * 128);
    for (int pp = 0; pp < 3; pp++) {
        int t0 = 3 * pp;
#pragma unroll
        for (int mi = 0; mi < 2; mi++) {
            int tile = mtBeg + mi;
            if (mi < nmt && tile >= t0 && tile < t0 + 3) {
#pragma unroll
                for (int nt = 0; nt < 4; nt++) {
                    int ol = nt * 16 + l15;
#pragma unroll
                    for (int r = 0; r < 4; r++) {
                        int p = tile * 16 + lg * 4 + r;
                        if (p < 100)
                            outS[(p - 48 * pp) * 68 + ol] =
                                fmaxf(acc[mi][nt][r] + bo[nt], 0.f);
                    }
                }
            }
        }
        __syncthreads();
        int nP = (pp == 2) ? 1 : 16;
        for (int idx = threadIdx.x; idx < nP * 64; idx += 256) {
            int Pl = idx >> 6, ol = idx & 63;
            int P = 16 * pp + Pl;
            int p = 3 * P - 48 * pp;
            float v0 = outS[p * 68 + ol];
            float v1 = outS[(p + 1) * 68 + ol];
            float v2 = outS[(p + 2) * 68 + ol];
            op[P * 128 + (nh << 6) + ol] = fmaxf(fmaxf(v0, v1), v2);
        }
        __syncthreads();
    }
}

// -------- K_A: conv1 both halves (1024, FIRST) || pass1 binning (1000) -----
__global__ __launch_bounds__(256) void k_A(
        const int* __restrict__ src, const int* __restrict__ dst,
        int* __restrict__ gcursor, unsigned* __restrict__ stage,
        const float* __restrict__ tgt, const float* __restrict__ K1,
        const float* __restrict__ cb1, __half* __restrict__ pool1) {
    __shared__ __align__(16) char smem[20160];   // conv1 s_in OR sort arrays
    int bx = blockIdx.x;
    if (bx < 1024) {                              // LPT: long conv1 first
        dev_conv1<5, 32, 16, 1000, 1008, 331, 6>(bx >> 1, bx & 1, tgt, K1, cb1,
                                                 pool1, (float*)smem);
        return;
    }
    int* hcnt  = (int*)smem;                 // [256] count -> scan -> cursor
    int* hbase = hcnt + 256;                 // [256] global bucket base
    int* lbase = hbase + 256;                // [256] local bucket base
    unsigned* sbuf = (unsigned*)(lbase + 256);      // [3200] sorted entries
    unsigned char* sbkt = (unsigned char*)(sbuf + NEPB); // [3200] bucket ids
    int t = threadIdx.x;
    int e0 = (bx - 1024) * NEPB;
    hcnt[t] = 0;
    __syncthreads();
    const int4* d4 = (const int4*)(dst + e0);
    for (int i = t; i < NEPB / 4; i += 256) {
        int4 d = d4[i];
        atomicAdd(&hcnt[d.x / BKTN], 1);
        atomicAdd(&hcnt[d.y / BKTN], 1);
        atomicAdd(&hcnt[d.z / BKTN], 1);
        atomicAdd(&hcnt[d.w / BKTN], 1);
    }
    __syncthreads();
    int myc = hcnt[t];
    hbase[t] = atomicAdd(&gcursor[t], myc);
    __syncthreads();
    // in-place inclusive scan of hcnt (Hillis-Steele)
#pragma unroll
    for (int off = 1; off < 256; off <<= 1) {
        int u = (t >= off) ? hcnt[t - off] : 0;
        __syncthreads();
        hcnt[t] += u;
        __syncthreads();
    }
    lbase[t] = hcnt[t] - myc;   // exclusive base
    hcnt[t] = 0;                // reuse as per-bucket cursor
    __syncthreads();
    const int4* s4 = (const int4*)(src + e0);
    for (int i = t; i < NEPB / 4; i += 256) {
        int4 d = d4[i];
        int4 s = s4[i];
        int ds[4] = {d.x, d.y, d.z, d.w};
        int ss[4] = {s.x, s.y, s.z, s.w};
#pragma unroll
        for (int j = 0; j < 4; j++) {
            int bkt = ds[j] / BKTN;
            int dloc = ds[j] - bkt * BKTN;
            int k = atomicAdd(&hcnt[bkt], 1);
            int pos = lbase[bkt] + k;
            sbuf[pos] = ((unsigned)dloc << 18) | (unsigned)ss[j];
            sbkt[pos] = (unsigned char)bkt;
        }
    }
    __syncthreads();
    // coalesced copy-out: consecutive i -> consecutive stage addresses
    for (int i = t; i < NEPB; i += 256) {
        unsigned v = sbuf[i];
        int bkt = sbkt[i];
        stage[hbase[bkt] + (i - lbase[bkt])] = v;
    }
}

// -------- K_Bp: pure pass2 (256 blocks; low VGPR, high occupancy) ----------
__global__ __launch_bounds__(256) void k_Bp(
        const unsigned* __restrict__ stage, const int* __restrict__ gcursor,
        int* __restrict__ rowptr, int* __restrict__ cnt, int* __restrict__ csr,
        const float* __restrict__ x, float4* __restrict__ dt1) {
    __shared__ int lcnt[BKTN];
    __shared__ int lpos[BKTN];
    __shared__ int partial[256];
    __shared__ int sbase;
    int t = threadIdx.x;
    int bkt = blockIdx.x;
    int tot = gcursor[t] - t * BKTCAP;
    partial[t] = tot;
    __syncthreads();
#pragma unroll
    for (int off = 1; off < 256; off <<= 1) {
        int u = (t >= off) ? partial[t - off] : 0;
        __syncthreads();
        partial[t] += u;
        __syncthreads();
    }
    if (t == 0) sbase = (bkt == 0) ? 0 : partial[bkt - 1];
    __syncthreads();
    int base = sbase;
    int n0 = bkt * BKTN;
    int ncnt = (NA - n0 < BKTN) ? (NA - n0) : BKTN;
    int eBeg = bkt * BKTCAP;
    int eCnt = gcursor[bkt] - eBeg;
    for (int i = t; i < BKTN; i += 256) lcnt[i] = 0;
    __syncthreads();
    for (int i = t; i < eCnt; i += 256)
        atomicAdd(&lcnt[stage[eBeg + i] >> 18], 1);
    __syncthreads();
    int mysum = 0;
#pragma unroll
    for (int j = 0; j < 4; j++) {
        int node = 4 * t + j;
        if (node < ncnt) mysum += lcnt[node];
    }
    partial[t] = mysum;
    __syncthreads();
#pragma unroll
    for (int off = 1; off < 256; off <<= 1) {
        int u = (t >= off) ? partial[t - off] : 0;
        __syncthreads();
        partial[t] += u;
        __syncthreads();
    }
    int running = partial[t] - mysum;
#pragma unroll
    for (int j = 0; j < 4; j++) {
        int node = 4 * t + j;
        if (node < ncnt) {
            lpos[node] = running;
            rowptr[n0 + node] = base + running;
            cnt[n0 + node] = lcnt[node];
            running += lcnt[node];
        }
    }
    __syncthreads();
    for (int i = t; i < eCnt; i += 256) {
        unsigned v = stage[eBeg + i];
        int dloc = v >> 18;
        int s = v & 0x3FFFF;
        int k = atomicAdd(&lpos[dloc], 1);
        csr[base + k] = s;
    }
    for (int i = t; i < ncnt; i += 256) {
        int n = n0 + i;
        float4 p = ((const float4*)x)[n];
        float dv = rsqrtf((float)lcnt[i] + 1.0f);
        dt1[n] = make_float4(dv * p.x, dv * p.y, dv * p.z, dv * p.w);
    }
}

// -------- K_B: conv2 MFMA (512) || coop-gather1+W1 -> dt2 (3125) -----------
// 4 lanes/node, 4-deep independent loads per iteration (latency-bound).
__global__ __launch_bounds__(256) void k_B(
        const __half* __restrict__ pool1, const __half* __restrict__ Wt2,
        const float* __restrict__ cb2, __half* __restrict__ pool2t,
        const float4* __restrict__ dt1, const int* __restrict__ rowptr,
        const int* __restrict__ cnt, const int* __restrict__ csr,
        const float* __restrict__ W1, const float* __restrict__ b1,
        float* __restrict__ dt2f) {
    __shared__ __align__(16) char smem[45696];
    int bx = blockIdx.x;
    if (bx < 512) {
        dev_conv2_mfma(bx, pool1, Wt2, cb2, pool2t, smem);
        return;
    }
    __shared__ float sW[16];
    if (threadIdx.x < 16) sW[threadIdx.x] = W1[threadIdx.x];
    __syncthreads();
    int n   = (bx - 512) * 64 + (threadIdx.x >> 2);   // always < NA
    int sub = threadIdx.x & 3;
    int cn = cnt[n];
    float dv = rsqrtf((float)cn + 1.0f);
    const int* row = csr + rowptr[n];
    float4 selfv = dt1[n];                            // broadcast load
    float4 acc = make_float4(0.f, 0.f, 0.f, 0.f);
    if (sub == 0) acc = selfv;
    int e = sub;
    for (; e + 12 < cn; e += 16) {                    // 4 independent loads
        float4 v0 = dt1[row[e]];
        float4 v1 = dt1[row[e + 4]];
        float4 v2 = dt1[row[e + 8]];
        float4 v3 = dt1[row[e + 12]];
        acc.x += (v0.x + v1.x) + (v2.x + v3.x);
        acc.y += (v0.y + v1.y) + (v2.y + v3.y);
        acc.z += (v0.z + v1.z) + (v2.z + v3.z);
        acc.w += (v0.w + v1.w) + (v2.w + v3.w);
    }
    for (; e < cn; e += 4) {
        float4 v = dt1[row[e]];
        acc.x += v.x; acc.y += v.y; acc.z += v.z; acc.w += v.w;
    }
    // butterfly over the 4-lane group
    acc.x += __shfl_xor(acc.x, 1); acc.y += __shfl_xor(acc.y, 1);
    acc.z += __shfl_xor(acc.z, 1); acc.w += __shfl_xor(acc.w, 1);
    acc.x += __shfl_xor(acc.x, 2); acc.y += __shfl_xor(acc.y, 2);
    acc.z += __shfl_xor(acc.z, 2); acc.w += __shfl_xor(acc.w, 2);
    float a[4] = {acc.x, acc.y, acc.z, acc.w};
    float s = 0.f;
#pragma unroll
    for (int k = 0; k < 4; k++) s = fmaf(a[k], sW[k * 4 + sub], s);
    float o = dv * fmaxf(fmaf(dv, s, b1[sub]), 0.f);  // dt2 = dv*relu(...)
    dt2f[(size_t)n * 4 + sub] = o;
}

// -------- K_C: conv3 N-split (1024) || coop-gather2+W2 -> dt3 (3125) -------
// launch_bounds(256,8): live set ~48 regs with 4-deep gather, still <=64.
__global__ __launch_bounds__(256, 8) void k_C(
        const __half* __restrict__ pool2t, const __half* __restrict__ Wt3,
        const float* __restrict__ cb3, float* __restrict__ pool3,
        const float4* __restrict__ dt2, const int* __restrict__ rowptr,
        const int* __restrict__ cnt, const int* __restrict__ csr,
        const float* __restrict__ W2, const float* __restrict__ b2,
        unsigned* __restrict__ dt3u) {
    __shared__ __align__(16) char smem[17280];
    int bx = blockIdx.x;
    if (bx < 1024) {
        dev_conv3_mfma(bx & 511, bx >> 9, pool2t, Wt3, cb3, pool3, smem);
        return;
    }
    __shared__ float sW[32];
    if (threadIdx.x < 32) sW[threadIdx.x] = W2[threadIdx.x];
    __syncthreads();
    int n   = (bx - 1024) * 64 + (threadIdx.x >> 2);
    int sub = threadIdx.x & 3;
    int cn = cnt[n];
    float dv = rsqrtf((float)cn + 1.0f);
    const int* row = csr + rowptr[n];
    float4 selfv = dt2[n];
    float4 acc = make_float4(0.f, 0.f, 0.f, 0.f);
    if (sub == 0) acc = selfv;
    int e = sub;
    for (; e + 12 < cn; e += 16) {                    // 4 independent loads
        float4 v0 = dt2[row[e]];
        float4 v1 = dt2[row[e + 4]];
        float4 v2 = dt2[row[e + 8]];
        float4 v3 = dt2[row[e + 12]];
        acc.x += (v0.x + v1.x) + (v2.x + v3.x);
        acc.y += (v0.y + v1.y) + (v2.y + v3.y);
        acc.z += (v0.z + v1.z) + (v2.z + v3.z);
        acc.w += (v0.w + v1.w) + (v2.w + v3.w);
    }
    for (; e < cn; e += 4) {
        float4 v = dt2[row[e]];
        acc.x += v.x; acc.y += v.y; acc.z += v.z; acc.w += v.w;
    }
    acc.x += __shfl_xor(acc.x, 1); acc.y += __shfl_xor(acc.y, 1);
    acc.z += __shfl_xor(acc.z, 1); acc.w += __shfl_xor(acc.w, 1);
    acc.x += __shfl_xor(acc.x, 2); acc.y += __shfl_xor(acc.y, 2);
    acc.z += __shfl_xor(acc.z, 2); acc.w += __shfl_xor(acc.w, 2);
    float a[4] = {acc.x, acc.y, acc.z, acc.w};
    int f0 = 2 * sub;
    float s0 = 0.f, s1 = 0.f;
#pragma unroll
    for (int k = 0; k < 4; k++) {
        s0 = fmaf(a[k], sW[k * 8 + f0], s0);
        s1 = fmaf(a[k], sW[k * 8 + f0 + 1], s1);
    }
    float o0 = dv * fmaxf(fmaf(dv, s0, b2[f0]), 0.f);
    float o1 = dv * fmaxf(fmaf(dv, s1, b2[f0 + 1]), 0.f);
    dt3u[(size_t)n * 4 + sub] = f2h(o0, o1);
}

// -------- K_D: coop-gather3(fp16)+W3+segmax (3125) || mean+Wxt (64) --------
__global__ __launch_bounds__(256) void k_D(
        const uint4* __restrict__ dt3, const int* __restrict__ rowptr,
        const int* __restrict__ cnt, const int* __restrict__ csr,
        const float* __restrict__ W3, const float* __restrict__ b3,
        const int* __restrict__ batch, unsigned* __restrict__ g,
        const float* __restrict__ pool3, const float* __restrict__ Wxt,
        const float* __restrict__ bxt, float* __restrict__ cx) {
    int bx = blockIdx.x;
    if (bx >= NGB) {
        __shared__ float sa[8 * 128];
        int b0 = (bx - NGB) * 8;
        for (int t = threadIdx.x; t < 8 * 128; t += 256) {
            int gg = t >> 7, k = t & 127;
            // pool3 layout [b][P=33][o=128]; lanes read consecutive o
            const float* r = pool3 + (size_t)(b0 + gg) * (33 * 128) + k;
            float s = 0.f;
#pragma unroll
            for (int p = 0; p < 33; p++) s += r[p * 128];
            sa[t] = s * (1.f / 33.f);
        }
        __syncthreads();
        int j = threadIdx.x;
        if (j >= 128) return;
        float bj = bxt[j];
        float acc[8];
#pragma unroll
        for (int gg = 0; gg < 8; gg++) acc[gg] = bj;
#pragma unroll 4
        for (int k = 0; k < 128; k++) {
            float w = Wxt[(size_t)k * 128 + j];
#pragma unroll
            for (int gg = 0; gg < 8; gg++) acc[gg] = fmaf(sa[gg * 128 + k], w, acc[gg]);
        }
#pragma unroll
        for (int gg = 0; gg < 8; gg++)
            cx[(size_t)(b0 + gg) * 128 + j] = fmaxf(acc[gg], 0.f);
        return;
    }
    __shared__ float sW[128];
    __shared__ unsigned sg[32];
    __shared__ int sbmin;
    if (threadIdx.x < 128) sW[threadIdx.x] = W3[threadIdx.x];
    if (threadIdx.x < 32) sg[threadIdx.x] = 0u;
    if (threadIdx.x == 0) sbmin = batch[bx * 64];
    __syncthreads();
    int n   = bx * 64 + (threadIdx.x >> 2);          // always < NA
    int sub = threadIdx.x & 3;
    int cn = cnt[n];
    float dv = rsqrtf((float)cn + 1.0f);
    const int* row = csr + rowptr[n];
    uint4 sv = dt3[n];
    float4 slo = h4f(sv.x, sv.y), shi = h4f(sv.z, sv.w);
    float a0 = 0.f, a1 = 0.f, a2 = 0.f, a3 = 0.f;
    float a4 = 0.f, a5 = 0.f, a6 = 0.f, a7 = 0.f;
    if (sub == 0) {
        a0 = slo.x; a1 = slo.y; a2 = slo.z; a3 = slo.w;
        a4 = shi.x; a5 = shi.y; a6 = shi.z; a7 = shi.w;
    }
    int e = sub;
    for (; e + 12 < cn; e += 16) {                   // 4 independent loads
        uint4 p0 = dt3[row[e]], p1 = dt3[row[e + 4]];
        uint4 p2 = dt3[row[e + 8]], p3 = dt3[row[e + 12]];
        float4 l0 = h4f(p0.x, p0.y), h0 = h4f(p0.z, p0.w);
        float4 l1 = h4f(p1.x, p1.y), h1 = h4f(p1.z, p1.w);
        float4 l2 = h4f(p2.x, p2.y), h2 = h4f(p2.z, p2.w);
        float4 l3 = h4f(p3.x, p3.y), h3v = h4f(p3.z, p3.w);
        a0 += (l0.x + l1.x) + (l2.x + l3.x);
        a1 += (l0.y + l1.y) + (l2.y + l3.y);
        a2 += (l0.z + l1.z) + (l2.z + l3.z);
        a3 += (l0.w + l1.w) + (l2.w + l3.w);
        a4 += (h0.x + h1.x) + (h2.x + h3v.x);
        a5 += (h0.y + h1.y) + (h2.y + h3v.y);
        a6 += (h0.z + h1.z) + (h2.z + h3v.z);
        a7 += (h0.w + h1.w) + (h2.w + h3v.w);
    }
    for (; e < cn; e += 4) {
        uint4 p = dt3[row[e]];
        float4 l = h4f(p.x, p.y), h = h4f(p.z, p.w);
        a0 += l.x; a1 += l.y; a2 += l.z; a3 += l.w;
        a4 += h.x; a5 += h.y; a6 += h.z; a7 += h.w;
    }
    a0 += __shfl_xor(a0, 1); a1 += __shfl_xor(a1, 1);
    a2 += __shfl_xor(a2, 1); a3 += __shfl_xor(a3, 1);
    a4 += __shfl_xor(a4, 1); a5 += __shfl_xor(a5, 1);
    a6 += __shfl_xor(a6, 1); a7 += __shfl_xor(a7, 1);
    a0 += __shfl_xor(a0, 2); a1 += __shfl_xor(a1, 2);
    a2 += __shfl_xor(a2, 2); a3 += __shfl_xor(a3, 2);
    a4 += __shfl_xor(a4, 2); a5 += __shfl_xor(a5, 2);
    a6 += __shfl_xor(a6, 2); a7 += __shfl_xor(a7, 2);
    float af[8] = {a0, a1, a2, a3, a4, a5, a6, a7};
    int rb = batch[n] - sbmin;
    if (rb > 1) rb = 1;
#pragma unroll
    for (int j = 0; j < 4; j++) {
        int f = sub * 4 + j;
        float s = 0.f;
#pragma unroll
        for (int k = 0; k < 8; k++) s = fmaf(af[k], sW[k * 16 + f], s);
        float r = fmaxf(fmaf(dv, s, b3[f]), 0.f);
        atomicMax(&sg[rb * 16 + f], __float_as_uint(r));
    }
    __syncthreads();
    if (threadIdx.x < 32) {
        unsigned v = sg[threadIdx.x];
        int rb2 = threadIdx.x >> 4, f = threadIdx.x & 15;
        int bbn = sbmin + rb2;
        if (v != 0u && bbn < NB) atomicMax(&g[bbn * 16 + f], v);
    }
}

// -------- head: g@Wg1 -> gp1 (relu), 256 blocks ----------------------------
__global__ __launch_bounds__(256) void k_head_g(
        const float* __restrict__ g, const float* __restrict__ Wg1,
        const float* __restrict__ bg1, float* __restrict__ gp1) {
    __shared__ float sa[8 * 16];
    int bx = blockIdx.x;
    int b0 = (bx >> 2) * 8;
    if (threadIdx.x < 128)
        sa[threadIdx.x] = g[b0 * 16 + threadIdx.x];
    __syncthreads();
    int j = (bx & 3) * 256 + threadIdx.x;
    float bj = bg1[j];
    float acc[8];
#pragma unroll
    for (int gg = 0; gg < 8; gg++) acc[gg] = bj;
#pragma unroll
    for (int k = 0; k < 16; k++) {
        float w = Wg1[(size_t)k * 1024 + j];
#pragma unroll
        for (int gg = 0; gg < 8; gg++) acc[gg] = fmaf(sa[gg * 16 + k], w, acc[gg]);
    }
#pragma unroll
    for (int gg = 0; gg < 8; gg++)
        gp1[(size_t)(b0 + gg) * 1024 + j] = fmaxf(acc[gg], 0.f);
}

// -------- gvec += (gp1 K-slice)@Wg2 ; grid (8,64), 16-deep batching --------
__global__ __launch_bounds__(256) void k_gvec_ks(
        const float* __restrict__ gp1, const float* __restrict__ Wg2,
        float* __restrict__ gvec) {
    __shared__ float sa[8 * 128];
    int k0 = blockIdx.x * 128;
    int b0 = blockIdx.y * 8;
    for (int t = threadIdx.x; t < 8 * 128; t += 256) {
        int gg = t >> 7, k = t & 127;
        sa[t] = gp1[(size_t)(b0 + gg) * 1024 + k0 + k];
    }
    __syncthreads();
    int j  = threadIdx.x & 127;
    int kh = (threadIdx.x >> 7) * 64;            // 0 or 64
    const float* Wp = Wg2 + (size_t)(k0 + kh) * 128 + j;
    float acc[8];
#pragma unroll
    for (int gg = 0; gg < 8; gg++) acc[gg] = 0.f;
    for (int k = 0; k < 64; k += 16) {
        float w[16];
#pragma unroll
        for (int u = 0; u < 16; u++) w[u] = Wp[(size_t)(k + u) * 128];
#pragma unroll
        for (int u = 0; u < 16; u++) {
#pragma unroll
            for (int gg = 0; gg < 8; gg++)
                acc[gg] = fmaf(sa[gg * 128 + kh + k + u], w[u], acc[gg]);
        }
    }
#pragma unroll
    for (int gg = 0; gg < 8; gg++)
        atomicAdd(&gvec[(size_t)(b0 + gg) * 128 + j], acc[gg]);
}

// -------- xf1 += ([gvec|cx] K-half)@Wf1 ; grid (8,64): 4j x 2kh ------------
__global__ __launch_bounds__(256) void k_cat2(
        const float* __restrict__ gvec, const float* __restrict__ cx,
        const float* __restrict__ Wf1, float* __restrict__ xf1) {
    __shared__ float sa[8 * 128];
    int jx = blockIdx.x & 3;
    int kh = blockIdx.x >> 2;                    // 0: gvec rows, 1: cx rows
    int b0 = blockIdx.y * 8;
    const float* A = kh ? cx : gvec;
    for (int t = threadIdx.x; t < 8 * 128; t += 256) {
        int gg = t >> 7, k = t & 127;
        sa[t] = A[(size_t)(b0 + gg) * 128 + k];
    }
    __syncthreads();
    int j = jx * 256 + threadIdx.x;
    const float* Wp = Wf1 + (size_t)(kh * 128) * 1024 + j;
    float acc[8];
#pragma unroll
    for (int gg = 0; gg < 8; gg++) acc[gg] = 0.f;
    for (int k = 0; k < 128; k += 16) {
        float w[16];
#pragma unroll
        for (int u = 0; u < 16; u++) w[u] = Wp[(size_t)(k + u) * 1024];
#pragma unroll
        for (int u = 0; u < 16; u++) {
#pragma unroll
            for (int gg = 0; gg < 8; gg++)
                acc[gg] = fmaf(sa[gg * 128 + k + u], w[u], acc[gg]);
        }
    }
#pragma unroll
    for (int gg = 0; gg < 8; gg++)
        atomicAdd(&xf1[(size_t)(b0 + gg) * 1024 + j], acc[gg]);
}

// -------- xf2 += relu(xf1 K-slice)@Wf2 ; grid (8,64): 2j x 4kc -------------
__global__ __launch_bounds__(256) void k_xf2_ks(
        const float* __restrict__ xf1, const float* __restrict__ Wf2,
        float* __restrict__ xf2) {
    __shared__ float sa[8 * 256];
    int jb = blockIdx.x & 1;
    int k0 = (blockIdx.x >> 1) * 256;
    int b0 = blockIdx.y * 8;
    for (int t = threadIdx.x; t < 8 * 256; t += 256) {
        int gg = t >> 8, k = t & 255;
        sa[t] = fmaxf(xf1[(size_t)(b0 + gg) * 1024 + k0 + k], 0.f);  // deferred relu
    }
    __syncthreads();
    int j = jb * 256 + threadIdx.x;
    const float* Wp = Wf2 + (size_t)k0 * 512 + j;
    float acc[8];
#pragma unroll
    for (int gg = 0; gg < 8; gg++) acc[gg] = 0.f;
    for (int k = 0; k < 256; k += 16) {
        float w[16];
#pragma unroll
        for (int u = 0; u < 16; u++) w[u] = Wp[(size_t)(k + u) * 512];
#pragma unroll
        for (int u = 0; u < 16; u++) {
#pragma unroll
            for (int gg = 0; gg < 8; gg++)
                acc[gg] = fmaf(sa[gg * 256 + k + u], w[u], acc[gg]);
        }
    }
#pragma unroll
    for (int gg = 0; gg < 8; gg++)
        atomicAdd(&xf2[(size_t)(b0 + gg) * 512 + j], acc[gg]);
}

// final 512->2 layer; applies the deferred relu on xf2; float4 A-loads
__global__ __launch_bounds__(256) void k_dense_out(
        const float* __restrict__ A, const float* __restrict__ W,
        const float* __restrict__ bias, float* __restrict__ out) {
    int idx = blockIdx.x * 256 + threadIdx.x;
    if (idx >= NB * 2) return;
    int b = idx >> 1, j = idx & 1;
    float s = bias[j];
    const float4* A4 = (const float4*)(A + (size_t)b * 512);
    for (int k4 = 0; k4 < 128; k4 += 8) {
        float4 av[8];
#pragma unroll
        for (int u = 0; u < 8; u++) av[u] = A4[k4 + u];
#pragma unroll
        for (int u = 0; u < 8; u++) {
            int kb = (k4 + u) * 4;
            s = fmaf(fmaxf(av[u].x, 0.f), W[(kb + 0) * 2 + j], s);
            s = fmaf(fmaxf(av[u].y, 0.f), W[(kb + 1) * 2 + j], s);
            s = fmaf(fmaxf(av[u].z, 0.f), W[(kb + 2) * 2 + j], s);
            s = fmaf(fmaxf(av[u].w, 0.f), W[(kb + 3) * 2 + j], s);
        }
    }
    out[idx] = s;
}

extern "C" void kernel_launch(void* const* d_in, const int* in_sizes, int n_in,
                              void* d_out, int out_size, void* d_ws, size_t ws_size,
                              hipStream_t stream) {
    (void)in_sizes; (void)n_in; (void)out_size; (void)ws_size;
    const float* x   = (const float*)d_in[0];
    const int*  ei   = (const int*)d_in[1];
    const int*  batch= (const int*)d_in[2];
    const float* tgt = (const float*)d_in[3];
    const float* W1  = (const float*)d_in[4];  const float* b1  = (const float*)d_in[5];
    const float* W2  = (const float*)d_in[6];  const float* b2  = (const float*)d_in[7];
    const float* W3  = (const float*)d_in[8];  const float* b3  = (const float*)d_in[9];
    const float* Wg1 = (const float*)d_in[10]; const float* bg1 = (const float*)d_in[11];
    const float* Wg2 = (const float*)d_in[12]; const float* bg2 = (const float*)d_in[13];
    const float* K1  = (const float*)d_in[14]; const float* cb1 = (const float*)d_in[15];
    const float* K2  = (const float*)d_in[16]; const float* cb2 = (const float*)d_in[17];
    const float* K3  = (const float*)d_in[18]; const float* cb3 = (const float*)d_in[19];
    const float* Wxt = (const float*)d_in[20]; const float* bxt = (const float*)d_in[21];
    const float* Wf1 = (const float*)d_in[22]; const float* bf1 = (const float*)d_in[23];
    const float* Wf2 = (const float*)d_in[24]; const float* bf2 = (const float*)d_in[25];
    const float* Wo  = (const float*)d_in[26]; const float* bo  = (const float*)d_in[27];
    const int* srcp = ei;        // edge_index[0]
    const int* dstp = ei + NE;   // edge_index[1]

    float* ws = (float*)d_ws;
    float4* dt1 = (float4*)ws; ws += (size_t)NA * 4;   // dis*x          (3.2 MB)
    float4* dt2 = (float4*)ws; ws += (size_t)NA * 4;   // dis*out1       (3.2 MB)
    uint4*  dt3 = (uint4*)ws;  ws += (size_t)NA * 4;   // dis*out2 fp16  (3.2 MB)
    float* g     = ws; ws += NB * 16;
    float* gp1   = ws; ws += NB * 1024;
    float* gvec  = ws; ws += NB * 128;
    float* cx    = ws; ws += NB * 128;
    float* xf1   = ws; ws += NB * 1024;
    float* xf2   = ws; ws += NB * 512;
    __half* pool1 = (__half*)ws; ws += (size_t)NB * 32 * 331;   // fp16 (half used)
    __half* pool2t = (__half*)ws; ws += (size_t)NB * 64 * 108;  // fp16 [b][P][64]
    float* pool3 = ws; ws += (size_t)NB * 128 * 33;             // fp32 [b][33][128]
    __half* Wt2 = (__half*)ws; ws += 64 * 256 / 2;              // fp16 tap-major
    __half* Wt3 = (__half*)ws; ws += 128 * 512 / 2;             // fp16 tap-major
    int*   cnt    = (int*)ws; ws += NA;
    int*   rowptr = (int*)ws; ws += NA;
    int*   csr    = (int*)ws; ws += NE;               // compact CSR
    int*   gcursor= (int*)ws; ws += NBKT;
    unsigned* stage = (unsigned*)ws; ws += (size_t)NBKT * BKTCAP; // 16.8 MB

    dim3 blk(256);

    k_init<<<2048, blk, 0, stream>>>((unsigned*)g, gcursor, gvec, bg2, xf2, bf2,
                                     xf1, bf1, K2, K3, Wt2, Wt3);
    // K_A: conv1 both halves (1024 first, LPT) || pass1 binning (1000)
    k_A<<<2024, blk, 0, stream>>>(srcp, dstp, gcursor, stage, tgt, K1, cb1, pool1);
    // K_Bp: pure pass2 (256)
    k_Bp<<<256, blk, 0, stream>>>(stage, gcursor, rowptr, cnt, csr, x, dt1);
    // K_B: conv2 (512) || coop-gather1 (3125)
    k_B<<<512 + NGB, blk, 0, stream>>>(pool1, Wt2, cb2, pool2t,
                                       dt1, rowptr, cnt, csr, W1, b1, (float*)dt2);
    // K_C: conv3 N-split (1024) || coop-gather2 (3125)
    k_C<<<1024 + NGB, blk, 0, stream>>>(pool2t, Wt3, cb3, pool3,
                                        dt2, rowptr, cnt, csr, W2, b2, (unsigned*)dt3);
    // K_D: coop-gather3 (3125) || mean+Wxt (64)
    k_D<<<NGB + 64, blk, 0, stream>>>(dt3, rowptr, cnt, csr, W3, b3,
                                      batch, (unsigned*)g, pool3, Wxt, bxt, cx);

    // dense head (latency-hiding: >=512 blocks, 16-deep load batching)
    k_head_g<<<256, blk, 0, stream>>>(g, Wg1, bg1, gp1);
    k_gvec_ks<<<dim3(8, 64), blk, 0, stream>>>(gp1, Wg2, gvec);
    k_cat2<<<dim3(8, 64), blk, 0, stream>>>(gvec, cx, Wf1, xf1);
    k_xf2_ks<<<dim3(8, 64), blk, 0, stream>>>(xf1, Wf2, xf2);
    k_dense_out<<<4, blk, 0, stream>>>(xf2, Wo, bo, (float*)d_out);
}